// Round 1
// baseline (8058.403 us; speedup 1.0000x reference)
//
#include <hip/hip_runtime.h>
#include <hip/hip_bf16.h>
#include <math.h>

#define NN 100000
#define NE 1000000
#define FIN 32
#define HIDC 64
#define NHD 2
#define DD 32

typedef unsigned int u32;
typedef unsigned short u16;

// ---------- helpers ----------
__device__ __forceinline__ float wsum(float v) {
  #pragma unroll
  for (int off = 32; off; off >>= 1) v += __shfl_xor(v, off, 64);
  return v;
}

__device__ __forceinline__ u16 f2bf(float f) {
  union { float f; u32 u; } c; c.f = f;
  u32 u = c.u;
  return (u16)((u + 0x7FFFu + ((u >> 16) & 1u)) >> 16);
}

// monotonic float->uint key for atomicMax on floats
__device__ __forceinline__ u32 fkey(float f) {
  union { float f; u32 u; } c; c.f = f;
  return (c.u & 0x80000000u) ? ~c.u : (c.u | 0x80000000u);
}
__device__ __forceinline__ float fdec(u32 k) {
  union { float f; u32 u; } c;
  c.u = (k & 0x80000000u) ? (k ^ 0x80000000u) : ~k;
  return c.f;
}
#define KEY_NEG_INF 0x007FFFFFu  // fkey(-inf)

// load NW*8 bf16 elements (16B-granular vector loads) and upconvert
template<int NW>
__device__ __forceinline__ void ldbf(const u16* __restrict__ p, float* f) {
  const uint4* p4 = (const uint4*)p;
  #pragma unroll
  for (int i = 0; i < NW; i++) {
    uint4 v = p4[i];
    u32 a[4] = {v.x, v.y, v.z, v.w};
    #pragma unroll
    for (int j = 0; j < 4; j++) {
      union { u32 u; float f; } lo, hi;
      lo.u = (a[j] & 0xFFFFu) << 16;
      hi.u = a[j] & 0xFFFF0000u;
      f[i * 8 + j * 2]     = lo.f;
      f[i * 8 + j * 2 + 1] = hi.f;
    }
  }
}

// ---------- kernels ----------

// zero aggregates / softmax denoms, init running-max keys to fkey(-inf)
__global__ __launch_bounds__(256) void k_init(
    float* __restrict__ agg_mac, float* __restrict__ agg_buf,
    float* __restrict__ s_mac, float* __restrict__ s_buf,
    u32* __restrict__ m_mac, u32* __restrict__ m_buf) {
  int i = blockIdx.x * 256 + threadIdx.x;
  if (i < NN * HIDC) { agg_mac[i] = 0.0f; agg_buf[i] = 0.0f; }
  if (i < NN * NHD) {
    s_mac[i] = 0.0f; s_buf[i] = 0.0f;
    m_mac[i] = KEY_NEG_INF; m_buf[i] = KEY_NEG_INF;
  }
}

// h = relu(LN(x @ W + b)); one 64-lane wave per row, 4 rows/block
__global__ __launch_bounds__(256) void k_enc(
    const float* __restrict__ x, const float* __restrict__ w,
    const float* __restrict__ b, const float* __restrict__ g,
    const float* __restrict__ be, float* __restrict__ h) {
  __shared__ float ws_[FIN * HIDC];
  __shared__ float xs[4][FIN];
  int tid = threadIdx.x;
  for (int i = tid; i < FIN * HIDC; i += 256) ws_[i] = w[i];
  int wp = tid >> 6, ln = tid & 63;
  int row = blockIdx.x * 4 + wp;
  if (ln < FIN) xs[wp][ln] = x[row * FIN + ln];
  __syncthreads();
  float acc = b[ln];
  #pragma unroll
  for (int i = 0; i < FIN; i++) acc = fmaf(xs[wp][i], ws_[i * HIDC + ln], acc);
  float mu = wsum(acc) * (1.0f / HIDC);
  float d = acc - mu;
  float var = wsum(d * d) * (1.0f / HIDC);
  float y = g[ln] * d * rsqrtf(var + 1e-5f) + be[ln];
  h[row * HIDC + ln] = fmaxf(y, 0.0f);
}

// q = h@Qw+Qb ; kt = einsum(h@Kw+Kb, a_rel) ; vt = einsum(h@Vw+Vb, m_rel)
__global__ __launch_bounds__(256) void k_kqv(
    const float* __restrict__ h,
    const float* __restrict__ kw, const float* __restrict__ kb,
    const float* __restrict__ qw, const float* __restrict__ qb,
    const float* __restrict__ vw, const float* __restrict__ vb,
    const float* __restrict__ ar, const float* __restrict__ mr,
    u16* __restrict__ qo, u16* __restrict__ kto, u16* __restrict__ vto) {
  __shared__ float hs[4][HIDC];
  __shared__ float ks[4][HIDC];
  __shared__ float vs[4][HIDC];
  int tid = threadIdx.x, wp = tid >> 6, ln = tid & 63;
  int row = blockIdx.x * 4 + wp;
  hs[wp][ln] = h[row * HIDC + ln];
  __syncthreads();
  float q = qb[ln], k = kb[ln], v = vb[ln];
  for (int i = 0; i < HIDC; i++) {
    float hv = hs[wp][i];
    q = fmaf(hv, qw[i * HIDC + ln], q);
    k = fmaf(hv, kw[i * HIDC + ln], k);
    v = fmaf(hv, vw[i * HIDC + ln], v);
  }
  qo[row * HIDC + ln] = f2bf(q);
  ks[wp][ln] = k;
  vs[wp][ln] = v;
  __syncthreads();
  int hd = ln >> 5, e = ln & 31;
  float kt = 0.0f, vt = 0.0f;
  for (int d = 0; d < DD; d++) {
    float ksv = ks[wp][hd * DD + d];
    float vsv = vs[wp][hd * DD + d];
    kt = fmaf(ksv, ar[hd * DD * DD + d * DD + e], kt);
    vt = fmaf(vsv, mr[hd * DD * DD + d * DD + e], vt);
  }
  kto[row * HIDC + ln] = f2bf(kt);
  vto[row * HIDC + ln] = f2bf(vt);
}

// pass A: alpha = p[h]/sqrt(D) * <q[dst], kt[src]> ; atomicMax per-dst max
__global__ __launch_bounds__(256) void k_alpha(
    const int* __restrict__ ei, const u16* __restrict__ q,
    const u16* __restrict__ kt, const float* __restrict__ p,
    float* __restrict__ alpha, u32* __restrict__ m) {
  int e = blockIdx.x * 256 + threadIdx.x;
  if (e >= NE) return;
  int s_ = ei[e], d_ = ei[NE + e];
  float qv[64], kv[64];
  ldbf<8>(q + (size_t)d_ * HIDC, qv);
  ldbf<8>(kt + (size_t)s_ * HIDC, kv);
  float d0 = 0.0f, d1 = 0.0f;
  #pragma unroll
  for (int i = 0; i < DD; i++) {
    d0 = fmaf(qv[i], kv[i], d0);
    d1 = fmaf(qv[DD + i], kv[DD + i], d1);
  }
  float a0 = d0 * p[0] * 0.17677669529663687f;  // 1/sqrt(32)
  float a1 = d1 * p[1] * 0.17677669529663687f;
  alpha[e * 2] = a0;
  alpha[e * 2 + 1] = a1;
  atomicMax(&m[d_ * 2], fkey(a0));
  atomicMax(&m[d_ * 2 + 1], fkey(a1));
}

// pass B: e = exp(alpha - m[dst]); accumulate denominator
__global__ __launch_bounds__(256) void k_exp(
    const int* __restrict__ ei, float* __restrict__ alpha,
    const u32* __restrict__ m, float* __restrict__ s) {
  int e = blockIdx.x * 256 + threadIdx.x;
  if (e >= NE) return;
  int d_ = ei[NE + e];
  float m0 = fdec(m[d_ * 2]), m1 = fdec(m[d_ * 2 + 1]);
  float e0 = expf(alpha[e * 2] - m0);
  float e1 = expf(alpha[e * 2 + 1] - m1);
  alpha[e * 2] = e0;
  alpha[e * 2 + 1] = e1;
  atomicAdd(&s[d_ * 2], e0);
  atomicAdd(&s[d_ * 2 + 1], e1);
}

// pass C: agg[dst] += (e / s[dst]) * vt[src]; one thread per (edge, head)
__global__ __launch_bounds__(256) void k_agg(
    const int* __restrict__ ei, const float* __restrict__ alpha,
    const float* __restrict__ s, const u16* __restrict__ vt,
    float* __restrict__ agg) {
  int t = blockIdx.x * 256 + threadIdx.x;
  if (t >= NE * NHD) return;
  int e = t >> 1, hd = t & 1;
  int s_ = ei[e], d_ = ei[NE + e];
  float w = alpha[e * 2 + hd] / (s[d_ * 2 + hd] + 1e-16f);
  float vv[DD];
  ldbf<4>(vt + (size_t)s_ * HIDC + hd * DD, vv);
  float* ap = agg + (size_t)d_ * HIDC + hd * DD;
  #pragma unroll
  for (int i = 0; i < DD; i++) atomicAdd(&ap[i], vv[i] * w);
}

// out = LN(sig(skip)*(gelu(agg)@Ow+Ob) + (1-sig(skip))*h + h)
__global__ __launch_bounds__(256) void k_out(
    const float* __restrict__ agg, const float* __restrict__ h,
    const float* __restrict__ ow, const float* __restrict__ ob,
    const float* __restrict__ skip, const float* __restrict__ lg,
    const float* __restrict__ lb, float* __restrict__ y) {
  __shared__ float gs[4][HIDC];
  int tid = threadIdx.x, wp = tid >> 6, ln = tid & 63;
  int row = blockIdx.x * 4 + wp;
  float av = agg[row * HIDC + ln];
  float hv = h[row * HIDC + ln];
  float ga = 0.5f * av * (1.0f + erff(av * 0.70710678118654752f));
  gs[wp][ln] = ga;
  __syncthreads();
  float a = ob[ln];
  for (int i = 0; i < HIDC; i++) a = fmaf(gs[wp][i], ow[i * HIDC + ln], a);
  float g = 1.0f / (1.0f + expf(-skip[0]));
  float t = g * a + (1.0f - g) * hv + hv;
  float mu = wsum(t) * (1.0f / HIDC);
  float d = t - mu;
  float var = wsum(d * d) * (1.0f / HIDC);
  y[row * HIDC + ln] = lg[ln] * d * rsqrtf(var + 1e-5f) + lb[ln];
}

// ---------- launch ----------
extern "C" void kernel_launch(void* const* d_in, const int* in_sizes, int n_in,
                              void* d_out, int out_size, void* d_ws, size_t ws_size,
                              hipStream_t stream) {
  const float* x_mac     = (const float*)d_in[0];
  const float* x_buf     = (const float*)d_in[1];
  const int*   ei_m2b    = (const int*)d_in[2];
  const int*   ei_b2m    = (const int*)d_in[3];
  const float* enc_w_mac = (const float*)d_in[4];
  const float* enc_b_mac = (const float*)d_in[5];
  const float* enc_g_mac = (const float*)d_in[6];
  const float* enc_be_mac= (const float*)d_in[7];
  const float* k_w_mac   = (const float*)d_in[8];
  const float* k_b_mac   = (const float*)d_in[9];
  const float* q_w_mac   = (const float*)d_in[10];
  const float* q_b_mac   = (const float*)d_in[11];
  const float* v_w_mac   = (const float*)d_in[12];
  const float* v_b_mac   = (const float*)d_in[13];
  const float* o_w_mac   = (const float*)d_in[14];
  const float* o_b_mac   = (const float*)d_in[15];
  const float* skip_mac  = (const float*)d_in[16];
  const float* enc_w_buf = (const float*)d_in[17];
  const float* enc_b_buf = (const float*)d_in[18];
  const float* enc_g_buf = (const float*)d_in[19];
  const float* enc_be_buf= (const float*)d_in[20];
  const float* k_w_buf   = (const float*)d_in[21];
  const float* k_b_buf   = (const float*)d_in[22];
  const float* q_w_buf   = (const float*)d_in[23];
  const float* q_b_buf   = (const float*)d_in[24];
  const float* v_w_buf   = (const float*)d_in[25];
  const float* v_b_buf   = (const float*)d_in[26];
  const float* o_w_buf   = (const float*)d_in[27];
  const float* o_b_buf   = (const float*)d_in[28];
  const float* skip_buf  = (const float*)d_in[29];
  const float* a_m2b     = (const float*)d_in[30];
  const float* m_m2b     = (const float*)d_in[31];
  const float* p_m2b     = (const float*)d_in[32];
  const float* a_b2m     = (const float*)d_in[33];
  const float* m_b2m     = (const float*)d_in[34];
  const float* p_b2m     = (const float*)d_in[35];
  const float* ln_g      = (const float*)d_in[36];
  const float* ln_b      = (const float*)d_in[37];

  char* ws = (char*)d_ws;
  size_t off = 0;
  auto take = [&](size_t bytes) -> char* {
    char* p = ws + off;
    off = (off + bytes + 255) & ~(size_t)255;
    return p;
  };
  float* h_mac   = (float*)take((size_t)NN * HIDC * 4);
  float* h_buf   = (float*)take((size_t)NN * HIDC * 4);
  float* agg_mac = (float*)take((size_t)NN * HIDC * 4);
  float* agg_buf = (float*)take((size_t)NN * HIDC * 4);
  u16*   q_mac   = (u16*)take((size_t)NN * HIDC * 2);
  u16*   kt_mac  = (u16*)take((size_t)NN * HIDC * 2);
  u16*   vt_mac  = (u16*)take((size_t)NN * HIDC * 2);
  u16*   q_buf   = (u16*)take((size_t)NN * HIDC * 2);
  u16*   kt_buf  = (u16*)take((size_t)NN * HIDC * 2);
  u16*   vt_buf  = (u16*)take((size_t)NN * HIDC * 2);
  u32*   m_mac   = (u32*)take((size_t)NN * NHD * 4);
  u32*   m_buf   = (u32*)take((size_t)NN * NHD * 4);
  float* s_mac   = (float*)take((size_t)NN * NHD * 4);
  float* s_buf   = (float*)take((size_t)NN * NHD * 4);
  float* alpha   = (float*)take((size_t)NE * NHD * 4);

  const int node_grid = NN / 4;               // 25000, exact
  const int edge_grid = (NE + 255) / 256;     // 3907
  const int eh_grid   = (NE * NHD + 255) / 256;

  k_init<<<node_grid, 256, 0, stream>>>(agg_mac, agg_buf, s_mac, s_buf, m_mac, m_buf);

  k_enc<<<node_grid, 256, 0, stream>>>(x_mac, enc_w_mac, enc_b_mac, enc_g_mac, enc_be_mac, h_mac);
  k_enc<<<node_grid, 256, 0, stream>>>(x_buf, enc_w_buf, enc_b_buf, enc_g_buf, enc_be_buf, h_buf);

  // mac is src of m2b; buf is src of b2m
  k_kqv<<<node_grid, 256, 0, stream>>>(h_mac, k_w_mac, k_b_mac, q_w_mac, q_b_mac,
                                       v_w_mac, v_b_mac, a_m2b, m_m2b,
                                       q_mac, kt_mac, vt_mac);
  k_kqv<<<node_grid, 256, 0, stream>>>(h_buf, k_w_buf, k_b_buf, q_w_buf, q_b_buf,
                                       v_w_buf, v_b_buf, a_b2m, m_b2m,
                                       q_buf, kt_buf, vt_buf);

  // relation m2b: src=mac, dst=buf
  k_alpha<<<edge_grid, 256, 0, stream>>>(ei_m2b, q_buf, kt_mac, p_m2b, alpha, m_buf);
  k_exp<<<edge_grid, 256, 0, stream>>>(ei_m2b, alpha, m_buf, s_buf);
  k_agg<<<eh_grid, 256, 0, stream>>>(ei_m2b, alpha, s_buf, vt_mac, agg_buf);

  // relation b2m: src=buf, dst=mac
  k_alpha<<<edge_grid, 256, 0, stream>>>(ei_b2m, q_mac, kt_buf, p_b2m, alpha, m_mac);
  k_exp<<<edge_grid, 256, 0, stream>>>(ei_b2m, alpha, m_mac, s_mac);
  k_agg<<<eh_grid, 256, 0, stream>>>(ei_b2m, alpha, s_mac, vt_buf, agg_mac);

  float* y = (float*)d_out;
  k_out<<<node_grid, 256, 0, stream>>>(agg_mac, h_mac, o_w_mac, o_b_mac, skip_mac, ln_g, ln_b, y);
  k_out<<<node_grid, 256, 0, stream>>>(agg_buf, h_buf, o_w_buf, o_b_buf, skip_buf, ln_g, ln_b, y + (size_t)NN * HIDC);
}

// Round 2
// 1063.217 us; speedup vs baseline: 7.5793x; 7.5793x over previous
//
#include <hip/hip_runtime.h>
#include <hip/hip_bf16.h>
#include <math.h>

#define NN 100000
#define NE 1000000
#define FIN 32
#define HIDC 64
#define NHD 2
#define DD 32

#define SCAN_BS 1024
#define NBLK ((NN + SCAN_BS - 1) / SCAN_BS)   // 98

typedef unsigned int u32;
typedef unsigned short u16;

// ---------- helpers ----------
__device__ __forceinline__ float wsum(float v) {
  #pragma unroll
  for (int off = 32; off; off >>= 1) v += __shfl_xor(v, off, 64);
  return v;
}

__device__ __forceinline__ u16 f2bf(float f) {
  union { float f; u32 u; } c; c.f = f;
  u32 u = c.u;
  return (u16)((u + 0x7FFFu + ((u >> 16) & 1u)) >> 16);
}

__device__ __forceinline__ float bf2f(u16 v) {
  union { u32 u; float f; } c; c.u = ((u32)v) << 16; return c.f;
}

// ---------- node kernels ----------

// h = relu(LN(x @ W + b)); one 64-lane wave per row, 4 rows/block
__global__ __launch_bounds__(256) void k_enc(
    const float* __restrict__ x, const float* __restrict__ w,
    const float* __restrict__ b, const float* __restrict__ g,
    const float* __restrict__ be, float* __restrict__ h) {
  __shared__ float ws_[FIN * HIDC];
  __shared__ float xs[4][FIN];
  int tid = threadIdx.x;
  for (int i = tid; i < FIN * HIDC; i += 256) ws_[i] = w[i];
  int wp = tid >> 6, ln = tid & 63;
  int row = blockIdx.x * 4 + wp;
  if (ln < FIN) xs[wp][ln] = x[row * FIN + ln];
  __syncthreads();
  float acc = b[ln];
  #pragma unroll
  for (int i = 0; i < FIN; i++) acc = fmaf(xs[wp][i], ws_[i * HIDC + ln], acc);
  float mu = wsum(acc) * (1.0f / HIDC);
  float d = acc - mu;
  float var = wsum(d * d) * (1.0f / HIDC);
  float y = g[ln] * d * rsqrtf(var + 1e-5f) + be[ln];
  h[row * HIDC + ln] = fmaxf(y, 0.0f);
}

// q = h@Qw+Qb ; kt = einsum(h@Kw+Kb, a_rel) ; vt = einsum(h@Vw+Vb, m_rel)
__global__ __launch_bounds__(256) void k_kqv(
    const float* __restrict__ h,
    const float* __restrict__ kw, const float* __restrict__ kb,
    const float* __restrict__ qw, const float* __restrict__ qb,
    const float* __restrict__ vw, const float* __restrict__ vb,
    const float* __restrict__ ar, const float* __restrict__ mr,
    u16* __restrict__ qo, u16* __restrict__ kto, u16* __restrict__ vto) {
  __shared__ float hs[4][HIDC];
  __shared__ float ks[4][HIDC];
  __shared__ float vs[4][HIDC];
  int tid = threadIdx.x, wp = tid >> 6, ln = tid & 63;
  int row = blockIdx.x * 4 + wp;
  hs[wp][ln] = h[row * HIDC + ln];
  __syncthreads();
  float q = qb[ln], k = kb[ln], v = vb[ln];
  for (int i = 0; i < HIDC; i++) {
    float hv = hs[wp][i];
    q = fmaf(hv, qw[i * HIDC + ln], q);
    k = fmaf(hv, kw[i * HIDC + ln], k);
    v = fmaf(hv, vw[i * HIDC + ln], v);
  }
  qo[row * HIDC + ln] = f2bf(q);
  ks[wp][ln] = k;
  vs[wp][ln] = v;
  __syncthreads();
  int hd = ln >> 5, e = ln & 31;
  float kt = 0.0f, vt = 0.0f;
  for (int d = 0; d < DD; d++) {
    float ksv = ks[wp][hd * DD + d];
    float vsv = vs[wp][hd * DD + d];
    kt = fmaf(ksv, ar[hd * DD * DD + d * DD + e], kt);
    vt = fmaf(vsv, mr[hd * DD * DD + d * DD + e], vt);
  }
  kto[row * HIDC + ln] = f2bf(kt);
  vto[row * HIDC + ln] = f2bf(vt);
}

// out = LN(sig(skip)*(gelu(agg)@Ow+Ob) + (1-sig(skip))*h + h)
__global__ __launch_bounds__(256) void k_out(
    const float* __restrict__ agg, const float* __restrict__ h,
    const float* __restrict__ ow, const float* __restrict__ ob,
    const float* __restrict__ skip, const float* __restrict__ lg,
    const float* __restrict__ lb, float* __restrict__ y) {
  __shared__ float gs[4][HIDC];
  int tid = threadIdx.x, wp = tid >> 6, ln = tid & 63;
  int row = blockIdx.x * 4 + wp;
  float av = agg[row * HIDC + ln];
  float hv = h[row * HIDC + ln];
  float ga = 0.5f * av * (1.0f + erff(av * 0.70710678118654752f));
  gs[wp][ln] = ga;
  __syncthreads();
  float a = ob[ln];
  for (int i = 0; i < HIDC; i++) a = fmaf(gs[wp][i], ow[i * HIDC + ln], a);
  float g = 1.0f / (1.0f + expf(-skip[0]));
  float t = g * a + (1.0f - g) * hv + hv;
  float mu = wsum(t) * (1.0f / HIDC);
  float d = t - mu;
  float var = wsum(d * d) * (1.0f / HIDC);
  y[row * HIDC + ln] = lg[ln] * d * rsqrtf(var + 1e-5f) + lb[ln];
}

// ---------- CSR build ----------

__global__ __launch_bounds__(SCAN_BS) void k_zero(u32* __restrict__ cnt) {
  int i = blockIdx.x * SCAN_BS + threadIdx.x;
  if (i < NN) cnt[i] = 0;
}

__global__ __launch_bounds__(256) void k_hist(const int* __restrict__ ei,
                                              u32* __restrict__ cnt) {
  int e = blockIdx.x * 256 + threadIdx.x;
  if (e < NE) atomicAdd(&cnt[ei[NE + e]], 1u);
}

// block-level inclusive scan -> exclusive per-element + block totals
__global__ __launch_bounds__(SCAN_BS) void k_scan1(
    const u32* __restrict__ cnt, u32* __restrict__ excl, u32* __restrict__ partials) {
  __shared__ u32 tmp[SCAN_BS];
  int t = threadIdx.x;
  int i = blockIdx.x * SCAN_BS + t;
  u32 v = (i < NN) ? cnt[i] : 0u;
  tmp[t] = v;
  __syncthreads();
  for (int off = 1; off < SCAN_BS; off <<= 1) {
    u32 add = (t >= off) ? tmp[t - off] : 0u;
    __syncthreads();
    tmp[t] += add;
    __syncthreads();
  }
  if (i < NN) excl[i] = tmp[t] - v;
  if (t == SCAN_BS - 1) partials[blockIdx.x] = tmp[t];
}

__global__ __launch_bounds__(128) void k_scan2(u32* __restrict__ partials) {
  __shared__ u32 t[NBLK];
  int i = threadIdx.x;
  if (i < NBLK) t[i] = partials[i];
  __syncthreads();
  if (i == 0) {
    u32 run = 0;
    for (int j = 0; j < NBLK; ++j) { u32 v = t[j]; t[j] = run; run += v; }
  }
  __syncthreads();
  if (i < NBLK) partials[i] = t[i];
}

__global__ __launch_bounds__(SCAN_BS) void k_scan3(
    const u32* __restrict__ excl, const u32* __restrict__ partials,
    u32* __restrict__ rowptr, u32* __restrict__ cursor) {
  int i = blockIdx.x * SCAN_BS + threadIdx.x;
  if (i < NN) {
    u32 v = excl[i] + partials[blockIdx.x];
    rowptr[i] = v;
    cursor[i] = v;
  }
  if (i == 0) rowptr[NN] = NE;
}

__global__ __launch_bounds__(256) void k_scatter(const int* __restrict__ ei,
                                                 u32* __restrict__ cursor,
                                                 int* __restrict__ csr_src) {
  int e = blockIdx.x * 256 + threadIdx.x;
  if (e < NE) {
    int d = ei[NE + e];
    u32 pos = atomicAdd(&cursor[d], 1u);
    csr_src[pos] = ei[e];
  }
}

// ---------- fused edge phase: alpha + online softmax + aggregate ----------
// one 64-lane wave per dst node; zero atomics
__global__ __launch_bounds__(256) void k_edge(
    const u32* __restrict__ rowptr, const int* __restrict__ csr,
    const u16* __restrict__ q, const u16* __restrict__ kt,
    const u16* __restrict__ vt, const float* __restrict__ p,
    float* __restrict__ agg) {
  int wid = (blockIdx.x << 2) + (threadIdx.x >> 6);  // dst node
  int ln = threadIdx.x & 63;
  int hd = ln >> 5;
  float qv = bf2f(q[(size_t)wid * HIDC + ln]);
  float pr = p[hd] * 0.17677669529663687f;  // p / sqrt(32)
  u32 j0 = rowptr[wid], j1 = rowptr[wid + 1];
  float m = -INFINITY, s = 0.0f, acc = 0.0f;
  for (u32 j = j0; j < j1; ++j) {
    int src = csr[j];
    float kv = bf2f(kt[(size_t)src * HIDC + ln]);
    float vv = bf2f(vt[(size_t)src * HIDC + ln]);
    float prod = qv * kv;
    #pragma unroll
    for (int off = 1; off < 32; off <<= 1) prod += __shfl_xor(prod, off, 64);
    float a = prod * pr;                 // per-head logit (uniform in 32-half)
    float mn = fmaxf(m, a);
    float c = __expf(m - mn);            // first iter: exp(-inf)=0
    float w = __expf(a - mn);
    s = fmaf(s, c, w);
    acc = acc * c + w * vv;
    m = mn;
  }
  agg[(size_t)wid * HIDC + ln] = acc / (s + 1e-16f);
}

// ---------- launch ----------
extern "C" void kernel_launch(void* const* d_in, const int* in_sizes, int n_in,
                              void* d_out, int out_size, void* d_ws, size_t ws_size,
                              hipStream_t stream) {
  const float* x_mac     = (const float*)d_in[0];
  const float* x_buf     = (const float*)d_in[1];
  const int*   ei_m2b    = (const int*)d_in[2];
  const int*   ei_b2m    = (const int*)d_in[3];
  const float* enc_w_mac = (const float*)d_in[4];
  const float* enc_b_mac = (const float*)d_in[5];
  const float* enc_g_mac = (const float*)d_in[6];
  const float* enc_be_mac= (const float*)d_in[7];
  const float* k_w_mac   = (const float*)d_in[8];
  const float* k_b_mac   = (const float*)d_in[9];
  const float* q_w_mac   = (const float*)d_in[10];
  const float* q_b_mac   = (const float*)d_in[11];
  const float* v_w_mac   = (const float*)d_in[12];
  const float* v_b_mac   = (const float*)d_in[13];
  const float* o_w_mac   = (const float*)d_in[14];
  const float* o_b_mac   = (const float*)d_in[15];
  const float* skip_mac  = (const float*)d_in[16];
  const float* enc_w_buf = (const float*)d_in[17];
  const float* enc_b_buf = (const float*)d_in[18];
  const float* enc_g_buf = (const float*)d_in[19];
  const float* enc_be_buf= (const float*)d_in[20];
  const float* k_w_buf   = (const float*)d_in[21];
  const float* k_b_buf   = (const float*)d_in[22];
  const float* q_w_buf   = (const float*)d_in[23];
  const float* q_b_buf   = (const float*)d_in[24];
  const float* v_w_buf   = (const float*)d_in[25];
  const float* v_b_buf   = (const float*)d_in[26];
  const float* o_w_buf   = (const float*)d_in[27];
  const float* o_b_buf   = (const float*)d_in[28];
  const float* skip_buf  = (const float*)d_in[29];
  const float* a_m2b     = (const float*)d_in[30];
  const float* m_m2b     = (const float*)d_in[31];
  const float* p_m2b     = (const float*)d_in[32];
  const float* a_b2m     = (const float*)d_in[33];
  const float* m_b2m     = (const float*)d_in[34];
  const float* p_b2m     = (const float*)d_in[35];
  const float* ln_g      = (const float*)d_in[36];
  const float* ln_b      = (const float*)d_in[37];

  char* ws = (char*)d_ws;
  size_t off = 0;
  auto take = [&](size_t bytes) -> char* {
    char* p = ws + off;
    off = (off + bytes + 255) & ~(size_t)255;
    return p;
  };
  float* h_mac   = (float*)take((size_t)NN * HIDC * 4);
  float* h_buf   = (float*)take((size_t)NN * HIDC * 4);
  float* agg_mac = (float*)take((size_t)NN * HIDC * 4);
  float* agg_buf = (float*)take((size_t)NN * HIDC * 4);
  u16*   q_mac   = (u16*)take((size_t)NN * HIDC * 2);
  u16*   kt_mac  = (u16*)take((size_t)NN * HIDC * 2);
  u16*   vt_mac  = (u16*)take((size_t)NN * HIDC * 2);
  u16*   q_buf   = (u16*)take((size_t)NN * HIDC * 2);
  u16*   kt_buf  = (u16*)take((size_t)NN * HIDC * 2);
  u16*   vt_buf  = (u16*)take((size_t)NN * HIDC * 2);
  u32*   cnt     = (u32*)take((size_t)NN * 4);
  u32*   excl    = (u32*)take((size_t)NN * 4);
  u32*   parts   = (u32*)take((size_t)NBLK * 4);
  u32*   rowptr  = (u32*)take((size_t)(NN + 1) * 4);
  u32*   cursor  = (u32*)take((size_t)NN * 4);
  int*   csr_src = (int*)take((size_t)NE * 4);

  const int node_grid = NN / 4;               // 25000, exact
  const int edge_grid = (NE + 255) / 256;     // 3907

  k_enc<<<node_grid, 256, 0, stream>>>(x_mac, enc_w_mac, enc_b_mac, enc_g_mac, enc_be_mac, h_mac);
  k_enc<<<node_grid, 256, 0, stream>>>(x_buf, enc_w_buf, enc_b_buf, enc_g_buf, enc_be_buf, h_buf);

  // mac is src of m2b; buf is src of b2m
  k_kqv<<<node_grid, 256, 0, stream>>>(h_mac, k_w_mac, k_b_mac, q_w_mac, q_b_mac,
                                       v_w_mac, v_b_mac, a_m2b, m_m2b,
                                       q_mac, kt_mac, vt_mac);
  k_kqv<<<node_grid, 256, 0, stream>>>(h_buf, k_w_buf, k_b_buf, q_w_buf, q_b_buf,
                                       v_w_buf, v_b_buf, a_b2m, m_b2m,
                                       q_buf, kt_buf, vt_buf);

  // ----- relation m2b: src=mac, dst=buf -----
  k_zero<<<NBLK, SCAN_BS, 0, stream>>>(cnt);
  k_hist<<<edge_grid, 256, 0, stream>>>(ei_m2b, cnt);
  k_scan1<<<NBLK, SCAN_BS, 0, stream>>>(cnt, excl, parts);
  k_scan2<<<1, 128, 0, stream>>>(parts);
  k_scan3<<<NBLK, SCAN_BS, 0, stream>>>(excl, parts, rowptr, cursor);
  k_scatter<<<edge_grid, 256, 0, stream>>>(ei_m2b, cursor, csr_src);
  k_edge<<<node_grid, 256, 0, stream>>>(rowptr, csr_src, q_buf, kt_mac, vt_mac, p_m2b, agg_buf);

  // ----- relation b2m: src=buf, dst=mac -----
  k_zero<<<NBLK, SCAN_BS, 0, stream>>>(cnt);
  k_hist<<<edge_grid, 256, 0, stream>>>(ei_b2m, cnt);
  k_scan1<<<NBLK, SCAN_BS, 0, stream>>>(cnt, excl, parts);
  k_scan2<<<1, 128, 0, stream>>>(parts);
  k_scan3<<<NBLK, SCAN_BS, 0, stream>>>(excl, parts, rowptr, cursor);
  k_scatter<<<edge_grid, 256, 0, stream>>>(ei_b2m, cursor, csr_src);
  k_edge<<<node_grid, 256, 0, stream>>>(rowptr, csr_src, q_mac, kt_buf, vt_buf, p_b2m, agg_mac);

  float* y = (float*)d_out;
  k_out<<<node_grid, 256, 0, stream>>>(agg_mac, h_mac, o_w_mac, o_b_mac, skip_mac, ln_g, ln_b, y);
  k_out<<<node_grid, 256, 0, stream>>>(agg_buf, h_buf, o_w_buf, o_b_buf, skip_buf, ln_g, ln_b, y + (size_t)NN * HIDC);
}

// Round 3
// 795.564 us; speedup vs baseline: 10.1292x; 1.3364x over previous
//
#include <hip/hip_runtime.h>
#include <hip/hip_bf16.h>
#include <math.h>

#define NN 100000
#define NE 1000000
#define FIN 32
#define HIDC 64
#define NHD 2
#define DD 32

#define SCAN_BS 1024
#define NBLK ((NN + SCAN_BS - 1) / SCAN_BS)   // 98

typedef unsigned int u32;
typedef unsigned short u16;

// ---------- helpers ----------
__device__ __forceinline__ float wsum(float v) {
  #pragma unroll
  for (int off = 32; off; off >>= 1) v += __shfl_xor(v, off, 64);
  return v;
}

__device__ __forceinline__ u16 f2bf(float f) {
  union { float f; u32 u; } c; c.f = f;
  u32 u = c.u;
  return (u16)((u + 0x7FFFu + ((u >> 16) & 1u)) >> 16);
}

__device__ __forceinline__ float bf2f(u16 v) {
  union { u32 u; float f; } c; c.u = ((u32)v) << 16; return c.f;
}

// ---------- node kernels ----------

// h = relu(LN(x @ W + b)); one 64-lane wave per row, 4 rows/block
__global__ __launch_bounds__(256) void k_enc(
    const float* __restrict__ x, const float* __restrict__ w,
    const float* __restrict__ b, const float* __restrict__ g,
    const float* __restrict__ be, float* __restrict__ h) {
  __shared__ float ws_[FIN * HIDC];
  __shared__ float xs[4][FIN];
  int tid = threadIdx.x;
  for (int i = tid; i < FIN * HIDC; i += 256) ws_[i] = w[i];
  int wp = tid >> 6, ln = tid & 63;
  int row = blockIdx.x * 4 + wp;
  if (ln < FIN) xs[wp][ln] = x[row * FIN + ln];
  __syncthreads();
  float acc = b[ln];
  #pragma unroll
  for (int i = 0; i < FIN; i++) acc = fmaf(xs[wp][i], ws_[i * HIDC + ln], acc);
  float mu = wsum(acc) * (1.0f / HIDC);
  float d = acc - mu;
  float var = wsum(d * d) * (1.0f / HIDC);
  float y = g[ln] * d * rsqrtf(var + 1e-5f) + be[ln];
  h[row * HIDC + ln] = fmaxf(y, 0.0f);
}

// fuse relation transform into weights:
// Wf[64][192]: cols 0..63 = qw; 64..127 = kw @ blockdiag(ar) * p/sqrt(D); 128..191 = vw @ blockdiag(mr)
// bf[192] likewise from biases.
__global__ __launch_bounds__(256) void k_fuse(
    const float* __restrict__ qw, const float* __restrict__ qb,
    const float* __restrict__ kw, const float* __restrict__ kb,
    const float* __restrict__ vw, const float* __restrict__ vb,
    const float* __restrict__ ar, const float* __restrict__ mr,
    const float* __restrict__ p, float* __restrict__ Wf, float* __restrict__ bfv) {
  int idx = blockIdx.x * 256 + threadIdx.x;
  if (idx < 64 * 192) {
    int i = idx / 192, c = idx % 192;
    float o;
    if (c < 64) {
      o = qw[i * 64 + c];
    } else {
      int e = c & 63, hd = e >> 5, ee = e & 31;
      bool isK = c < 128;
      const float* M = isK ? ar : mr;
      const float* W = isK ? kw : vw;
      float s = 0.0f;
      #pragma unroll
      for (int d = 0; d < 32; ++d)
        s += W[i * 64 + hd * 32 + d] * M[hd * 32 * 32 + d * 32 + ee];
      if (isK) s *= p[hd] * 0.17677669529663687f;
      o = s;
    }
    Wf[i * 192 + c] = o;
  } else if (idx < 64 * 192 + 192) {
    int c = idx - 64 * 192;
    float o;
    if (c < 64) {
      o = qb[c];
    } else {
      int e = c & 63, hd = e >> 5, ee = e & 31;
      bool isK = c < 128;
      const float* M = isK ? ar : mr;
      const float* B = isK ? kb : vb;
      float s = 0.0f;
      #pragma unroll
      for (int d = 0; d < 32; ++d)
        s += B[hd * 32 + d] * M[hd * 32 * 32 + d * 32 + ee];
      if (isK) s *= p[hd] * 0.17677669529663687f;
      o = s;
    }
    bfv[c] = o;
  }
}

// out[100k x 192] = h[100k x 64] @ Wf[64 x 192] + bf : register-blocked LDS GEMM.
// 64-row tile per block; thread (rg,cg) computes rows rg*4..+3, cols {cg*4+j*64 | j=0..2}.
// q cols -> bf16 qo; kt/vt col pairs (same e) -> packed u32 kvt.
__global__ __launch_bounds__(256) void k_kqv2(
    const float* __restrict__ h, const float* __restrict__ Wf,
    const float* __restrict__ bfv,
    u16* __restrict__ qo, u32* __restrict__ kvt) {
  __shared__ float ws_[64 * 192];    // 48 KB, k-major
  __shared__ float hs[64][65];       // 16.6 KB, padded rows
  int t = threadIdx.x;
  int r0 = blockIdx.x * 64;
  for (int i = t; i < 64 * 192 / 4; i += 256)
    ((float4*)ws_)[i] = ((const float4*)Wf)[i];
  for (int i = t; i < 64 * 16; i += 256) {
    int row = i >> 4, c4 = i & 15;
    int gr = r0 + row; if (gr >= NN) gr = NN - 1;
    float4 v = *(const float4*)&h[(size_t)gr * 64 + c4 * 4];
    hs[row][c4 * 4 + 0] = v.x; hs[row][c4 * 4 + 1] = v.y;
    hs[row][c4 * 4 + 2] = v.z; hs[row][c4 * 4 + 3] = v.w;
  }
  __syncthreads();
  int rg = t & 15, cg = t >> 4;
  float acc[3][4][4];
  #pragma unroll
  for (int j = 0; j < 3; j++) {
    #pragma unroll
    for (int c = 0; c < 4; c++) {
      float bv = bfv[j * 64 + cg * 4 + c];
      #pragma unroll
      for (int r = 0; r < 4; r++) acc[j][r][c] = bv;
    }
  }
  for (int k = 0; k < 64; ++k) {
    float a0 = hs[rg * 4 + 0][k];
    float a1 = hs[rg * 4 + 1][k];
    float a2 = hs[rg * 4 + 2][k];
    float a3 = hs[rg * 4 + 3][k];
    #pragma unroll
    for (int j = 0; j < 3; j++) {
      float4 w = *(const float4*)&ws_[k * 192 + j * 64 + cg * 4];
      acc[j][0][0] = fmaf(a0, w.x, acc[j][0][0]);
      acc[j][0][1] = fmaf(a0, w.y, acc[j][0][1]);
      acc[j][0][2] = fmaf(a0, w.z, acc[j][0][2]);
      acc[j][0][3] = fmaf(a0, w.w, acc[j][0][3]);
      acc[j][1][0] = fmaf(a1, w.x, acc[j][1][0]);
      acc[j][1][1] = fmaf(a1, w.y, acc[j][1][1]);
      acc[j][1][2] = fmaf(a1, w.z, acc[j][1][2]);
      acc[j][1][3] = fmaf(a1, w.w, acc[j][1][3]);
      acc[j][2][0] = fmaf(a2, w.x, acc[j][2][0]);
      acc[j][2][1] = fmaf(a2, w.y, acc[j][2][1]);
      acc[j][2][2] = fmaf(a2, w.z, acc[j][2][2]);
      acc[j][2][3] = fmaf(a2, w.w, acc[j][2][3]);
      acc[j][3][0] = fmaf(a3, w.x, acc[j][3][0]);
      acc[j][3][1] = fmaf(a3, w.y, acc[j][3][1]);
      acc[j][3][2] = fmaf(a3, w.z, acc[j][3][2]);
      acc[j][3][3] = fmaf(a3, w.w, acc[j][3][3]);
    }
  }
  #pragma unroll
  for (int r = 0; r < 4; ++r) {
    int gr = r0 + rg * 4 + r;
    if (gr >= NN) break;
    // q: pack col pairs
    u32 q0 = (u32)f2bf(acc[0][r][0]) | ((u32)f2bf(acc[0][r][1]) << 16);
    u32 q1 = (u32)f2bf(acc[0][r][2]) | ((u32)f2bf(acc[0][r][3]) << 16);
    *(u32*)&qo[(size_t)gr * 64 + cg * 4]     = q0;
    *(u32*)&qo[(size_t)gr * 64 + cg * 4 + 2] = q1;
    #pragma unroll
    for (int c = 0; c < 4; ++c) {
      u32 kv = (u32)f2bf(acc[1][r][c]) | ((u32)f2bf(acc[2][r][c]) << 16);
      kvt[(size_t)gr * 64 + cg * 4 + c] = kv;
    }
  }
}

// out = LN(sig(skip)*(gelu(agg)@Ow+Ob) + (1-sig(skip))*h + h), ow staged in LDS
__global__ __launch_bounds__(256) void k_out(
    const float* __restrict__ agg, const float* __restrict__ h,
    const float* __restrict__ ow, const float* __restrict__ ob,
    const float* __restrict__ skip, const float* __restrict__ lg,
    const float* __restrict__ lb, float* __restrict__ y) {
  __shared__ float ows[HIDC * HIDC];
  __shared__ float gs[4][HIDC];
  int tid = threadIdx.x, wp = tid >> 6, ln = tid & 63;
  for (int i = tid; i < HIDC * HIDC / 4; i += 256)
    ((float4*)ows)[i] = ((const float4*)ow)[i];
  int row = blockIdx.x * 4 + wp;
  float av = agg[row * HIDC + ln];
  float hv = h[row * HIDC + ln];
  float ga = 0.5f * av * (1.0f + erff(av * 0.70710678118654752f));
  gs[wp][ln] = ga;
  __syncthreads();
  float a = ob[ln];
  #pragma unroll 8
  for (int i = 0; i < HIDC; i++) a = fmaf(gs[wp][i], ows[i * HIDC + ln], a);
  float g = 1.0f / (1.0f + expf(-skip[0]));
  float t = g * a + (1.0f - g) * hv + hv;
  float mu = wsum(t) * (1.0f / HIDC);
  float d = t - mu;
  float var = wsum(d * d) * (1.0f / HIDC);
  y[row * HIDC + ln] = lg[ln] * d * rsqrtf(var + 1e-5f) + lb[ln];
}

// ---------- CSR build ----------

__global__ __launch_bounds__(SCAN_BS) void k_zero(u32* __restrict__ cnt) {
  int i = blockIdx.x * SCAN_BS + threadIdx.x;
  if (i < NN) cnt[i] = 0;
}

__global__ __launch_bounds__(256) void k_hist(const int* __restrict__ ei,
                                              u32* __restrict__ cnt) {
  int e = blockIdx.x * 256 + threadIdx.x;
  if (e < NE) atomicAdd(&cnt[ei[NE + e]], 1u);
}

__global__ __launch_bounds__(SCAN_BS) void k_scan1(
    const u32* __restrict__ cnt, u32* __restrict__ excl, u32* __restrict__ partials) {
  __shared__ u32 tmp[SCAN_BS];
  int t = threadIdx.x;
  int i = blockIdx.x * SCAN_BS + t;
  u32 v = (i < NN) ? cnt[i] : 0u;
  tmp[t] = v;
  __syncthreads();
  for (int off = 1; off < SCAN_BS; off <<= 1) {
    u32 add = (t >= off) ? tmp[t - off] : 0u;
    __syncthreads();
    tmp[t] += add;
    __syncthreads();
  }
  if (i < NN) excl[i] = tmp[t] - v;
  if (t == SCAN_BS - 1) partials[blockIdx.x] = tmp[t];
}

__global__ __launch_bounds__(128) void k_scan2(u32* __restrict__ partials) {
  __shared__ u32 t[NBLK];
  int i = threadIdx.x;
  if (i < NBLK) t[i] = partials[i];
  __syncthreads();
  if (i == 0) {
    u32 run = 0;
    for (int j = 0; j < NBLK; ++j) { u32 v = t[j]; t[j] = run; run += v; }
  }
  __syncthreads();
  if (i < NBLK) partials[i] = t[i];
}

__global__ __launch_bounds__(SCAN_BS) void k_scan3(
    const u32* __restrict__ excl, const u32* __restrict__ partials,
    u32* __restrict__ rowptr, u32* __restrict__ cursor) {
  int i = blockIdx.x * SCAN_BS + threadIdx.x;
  if (i < NN) {
    u32 v = excl[i] + partials[blockIdx.x];
    rowptr[i] = v;
    cursor[i] = v;
  }
  if (i == 0) rowptr[NN] = NE;
}

__global__ __launch_bounds__(256) void k_scatter(const int* __restrict__ ei,
                                                 u32* __restrict__ cursor,
                                                 int* __restrict__ csr_src) {
  int e = blockIdx.x * 256 + threadIdx.x;
  if (e < NE) {
    int d = ei[NE + e];
    u32 pos = atomicAdd(&cursor[d], 1u);
    csr_src[pos] = ei[e];
  }
}

// ---------- fused edge phase ----------
// one wave per dst; kvt packed (kt lo16 | vt hi16), p/sqrt(D) pre-folded into kt
__global__ __launch_bounds__(256) void k_edge(
    const u32* __restrict__ rowptr, const int* __restrict__ csr,
    const u16* __restrict__ q, const u32* __restrict__ kvt,
    float* __restrict__ agg) {
  int wid = (blockIdx.x << 2) + (threadIdx.x >> 6);
  int ln = threadIdx.x & 63;
  float qv = bf2f(q[(size_t)wid * HIDC + ln]);
  u32 j0 = rowptr[wid], j1 = rowptr[wid + 1];
  float m = -INFINITY, s = 0.0f, acc = 0.0f;
  for (u32 j = j0; j < j1; ++j) {
    int src = csr[j];
    u32 w = kvt[(size_t)src * 64 + ln];
    float kv = bf2f((u16)(w & 0xFFFFu));
    float vv = bf2f((u16)(w >> 16));
    float prod = qv * kv;
    #pragma unroll
    for (int off = 1; off < 32; off <<= 1) prod += __shfl_xor(prod, off, 64);
    float a = prod;                      // scale pre-folded
    float mn = fmaxf(m, a);
    float c = __expf(m - mn);
    float ww = __expf(a - mn);
    s = fmaf(s, c, ww);
    acc = acc * c + ww * vv;
    m = mn;
  }
  agg[(size_t)wid * HIDC + ln] = acc / (s + 1e-16f);
}

// ---------- launch ----------
extern "C" void kernel_launch(void* const* d_in, const int* in_sizes, int n_in,
                              void* d_out, int out_size, void* d_ws, size_t ws_size,
                              hipStream_t stream) {
  const float* x_mac     = (const float*)d_in[0];
  const float* x_buf     = (const float*)d_in[1];
  const int*   ei_m2b    = (const int*)d_in[2];
  const int*   ei_b2m    = (const int*)d_in[3];
  const float* enc_w_mac = (const float*)d_in[4];
  const float* enc_b_mac = (const float*)d_in[5];
  const float* enc_g_mac = (const float*)d_in[6];
  const float* enc_be_mac= (const float*)d_in[7];
  const float* k_w_mac   = (const float*)d_in[8];
  const float* k_b_mac   = (const float*)d_in[9];
  const float* q_w_mac   = (const float*)d_in[10];
  const float* q_b_mac   = (const float*)d_in[11];
  const float* v_w_mac   = (const float*)d_in[12];
  const float* v_b_mac   = (const float*)d_in[13];
  const float* o_w_mac   = (const float*)d_in[14];
  const float* o_b_mac   = (const float*)d_in[15];
  const float* skip_mac  = (const float*)d_in[16];
  const float* enc_w_buf = (const float*)d_in[17];
  const float* enc_b_buf = (const float*)d_in[18];
  const float* enc_g_buf = (const float*)d_in[19];
  const float* enc_be_buf= (const float*)d_in[20];
  const float* k_w_buf   = (const float*)d_in[21];
  const float* k_b_buf   = (const float*)d_in[22];
  const float* q_w_buf   = (const float*)d_in[23];
  const float* q_b_buf   = (const float*)d_in[24];
  const float* v_w_buf   = (const float*)d_in[25];
  const float* v_b_buf   = (const float*)d_in[26];
  const float* o_w_buf   = (const float*)d_in[27];
  const float* o_b_buf   = (const float*)d_in[28];
  const float* skip_buf  = (const float*)d_in[29];
  const float* a_m2b     = (const float*)d_in[30];
  const float* m_m2b     = (const float*)d_in[31];
  const float* p_m2b     = (const float*)d_in[32];
  const float* a_b2m     = (const float*)d_in[33];
  const float* m_b2m     = (const float*)d_in[34];
  const float* p_b2m     = (const float*)d_in[35];
  const float* ln_g      = (const float*)d_in[36];
  const float* ln_b      = (const float*)d_in[37];

  char* ws = (char*)d_ws;
  size_t off = 0;
  auto take = [&](size_t bytes) -> char* {
    char* p = ws + off;
    off = (off + bytes + 255) & ~(size_t)255;
    return p;
  };
  float* h_mac   = (float*)take((size_t)NN * HIDC * 4);
  float* h_buf   = (float*)take((size_t)NN * HIDC * 4);
  float* agg_mac = (float*)take((size_t)NN * HIDC * 4);
  float* agg_buf = (float*)take((size_t)NN * HIDC * 4);
  u16*   q_mac   = (u16*)take((size_t)NN * HIDC * 2);
  u16*   q_buf   = (u16*)take((size_t)NN * HIDC * 2);
  u32*   kvt_mac = (u32*)take((size_t)NN * 64 * 4);
  u32*   kvt_buf = (u32*)take((size_t)NN * 64 * 4);
  float* Wf_mac  = (float*)take((size_t)64 * 192 * 4);
  float* bf_mac  = (float*)take((size_t)192 * 4);
  float* Wf_buf  = (float*)take((size_t)64 * 192 * 4);
  float* bf_buf  = (float*)take((size_t)192 * 4);
  u32*   cnt     = (u32*)take((size_t)NN * 4);
  u32*   excl    = (u32*)take((size_t)NN * 4);
  u32*   parts   = (u32*)take((size_t)NBLK * 4);
  u32*   rowptr  = (u32*)take((size_t)(NN + 1) * 4);
  u32*   cursor  = (u32*)take((size_t)NN * 4);
  int*   csr_src = (int*)take((size_t)NE * 4);

  const int node_grid = NN / 4;               // 25000
  const int edge_grid = (NE + 255) / 256;     // 3907
  const int kqv_grid  = (NN + 63) / 64;       // 1563
  const int fuse_grid = (64 * 192 + 192 + 255) / 256;  // 49

  k_enc<<<node_grid, 256, 0, stream>>>(x_mac, enc_w_mac, enc_b_mac, enc_g_mac, enc_be_mac, h_mac);
  k_enc<<<node_grid, 256, 0, stream>>>(x_buf, enc_w_buf, enc_b_buf, enc_g_buf, enc_be_buf, h_buf);

  // mac is src of m2b (uses a_m2b/m_m2b/p_m2b); buf is src of b2m
  k_fuse<<<fuse_grid, 256, 0, stream>>>(q_w_mac, q_b_mac, k_w_mac, k_b_mac, v_w_mac, v_b_mac,
                                        a_m2b, m_m2b, p_m2b, Wf_mac, bf_mac);
  k_fuse<<<fuse_grid, 256, 0, stream>>>(q_w_buf, q_b_buf, k_w_buf, k_b_buf, v_w_buf, v_b_buf,
                                        a_b2m, m_b2m, p_b2m, Wf_buf, bf_buf);
  k_kqv2<<<kqv_grid, 256, 0, stream>>>(h_mac, Wf_mac, bf_mac, q_mac, kvt_mac);
  k_kqv2<<<kqv_grid, 256, 0, stream>>>(h_buf, Wf_buf, bf_buf, q_buf, kvt_buf);

  // ----- relation m2b: src=mac, dst=buf -----
  k_zero<<<NBLK, SCAN_BS, 0, stream>>>(cnt);
  k_hist<<<edge_grid, 256, 0, stream>>>(ei_m2b, cnt);
  k_scan1<<<NBLK, SCAN_BS, 0, stream>>>(cnt, excl, parts);
  k_scan2<<<1, 128, 0, stream>>>(parts);
  k_scan3<<<NBLK, SCAN_BS, 0, stream>>>(excl, parts, rowptr, cursor);
  k_scatter<<<edge_grid, 256, 0, stream>>>(ei_m2b, cursor, csr_src);
  k_edge<<<node_grid, 256, 0, stream>>>(rowptr, csr_src, q_buf, kvt_mac, agg_buf);

  // ----- relation b2m: src=buf, dst=mac -----
  k_zero<<<NBLK, SCAN_BS, 0, stream>>>(cnt);
  k_hist<<<edge_grid, 256, 0, stream>>>(ei_b2m, cnt);
  k_scan1<<<NBLK, SCAN_BS, 0, stream>>>(cnt, excl, parts);
  k_scan2<<<1, 128, 0, stream>>>(parts);
  k_scan3<<<NBLK, SCAN_BS, 0, stream>>>(excl, parts, rowptr, cursor);
  k_scatter<<<edge_grid, 256, 0, stream>>>(ei_b2m, cursor, csr_src);
  k_edge<<<node_grid, 256, 0, stream>>>(rowptr, csr_src, q_mac, kvt_buf, agg_mac);

  float* y = (float*)d_out;
  k_out<<<node_grid, 256, 0, stream>>>(agg_mac, h_mac, o_w_mac, o_b_mac, skip_mac, ln_g, ln_b, y);
  k_out<<<node_grid, 256, 0, stream>>>(agg_buf, h_buf, o_w_buf, o_b_buf, skip_buf, ln_g, ln_b, y + (size_t)NN * HIDC);
}

// Round 4
// 602.171 us; speedup vs baseline: 13.3823x; 1.3212x over previous
//
#include <hip/hip_runtime.h>
#include <hip/hip_bf16.h>
#include <math.h>

#define NN 100000
#define NN2 200000
#define NE 1000000
#define FIN 32
#define HIDC 64

#define SCAN_BS 1024
#define NBLK2 ((NN2 + SCAN_BS - 1) / SCAN_BS)   // 196
#define KQV_BLKS 1563                            // ceil(NN/64)

typedef unsigned int u32;
typedef unsigned short u16;

// ---------- helpers ----------
__device__ __forceinline__ float wsum(float v) {
  #pragma unroll
  for (int off = 32; off; off >>= 1) v += __shfl_xor(v, off, 64);
  return v;
}

__device__ __forceinline__ u16 f2bf(float f) {
  union { float f; u32 u; } c; c.f = f;
  u32 u = c.u;
  return (u16)((u + 0x7FFFu + ((u >> 16) & 1u)) >> 16);
}

__device__ __forceinline__ float bf2f(u32 v) {  // low 16 bits = bf16
  union { u32 u; float f; } c; c.u = v << 16; return c.f;
}

// ---------- node kernels (merged over both types, global row ids) ----------

// h = relu(LN(x @ W + b)); one wave per row, 4 rows/block; 50000 blocks
__global__ __launch_bounds__(256) void k_enc(
    const float* __restrict__ x_mac, const float* __restrict__ x_buf,
    const float* __restrict__ w_mac, const float* __restrict__ b_mac,
    const float* __restrict__ g_mac, const float* __restrict__ be_mac,
    const float* __restrict__ w_buf, const float* __restrict__ b_buf,
    const float* __restrict__ g_buf, const float* __restrict__ be_buf,
    float* __restrict__ h) {
  __shared__ float ws_[FIN * HIDC];
  __shared__ float xs[4][FIN];
  int tid = threadIdx.x;
  int wp = tid >> 6, ln = tid & 63;
  int row = blockIdx.x * 4 + wp;                 // block type-uniform (NN%4==0)
  int type = (blockIdx.x * 4) >= NN;
  const float* w  = type ? w_buf  : w_mac;
  const float* b  = type ? b_buf  : b_mac;
  const float* g  = type ? g_buf  : g_mac;
  const float* be = type ? be_buf : be_mac;
  const float* x  = type ? (x_buf - (size_t)NN * FIN) : x_mac;
  for (int i = tid; i < FIN * HIDC; i += 256) ws_[i] = w[i];
  if (ln < FIN) xs[wp][ln] = x[(size_t)row * FIN + ln];
  __syncthreads();
  float acc = b[ln];
  #pragma unroll
  for (int i = 0; i < FIN; i++) acc = fmaf(xs[wp][i], ws_[i * HIDC + ln], acc);
  float mu = wsum(acc) * (1.0f / HIDC);
  float d = acc - mu;
  float var = wsum(d * d) * (1.0f / HIDC);
  float y = g[ln] * d * rsqrtf(var + 1e-5f) + be[ln];
  h[(size_t)row * HIDC + ln] = fmaxf(y, 0.0f);
}

// fused projection weights, both types: Wf[type][64][192], bf[type][192]
// cols 0..63 = qw; 64..127 = kw@blockdiag(ar)*p/sqrt(D); 128..191 = vw@blockdiag(mr)
#define FUSE_T (64 * 192 + 192)
__global__ __launch_bounds__(256) void k_fuse(
    const float* __restrict__ qw0, const float* __restrict__ qb0,
    const float* __restrict__ kw0, const float* __restrict__ kb0,
    const float* __restrict__ vw0, const float* __restrict__ vb0,
    const float* __restrict__ ar0, const float* __restrict__ mr0,
    const float* __restrict__ p0,
    const float* __restrict__ qw1, const float* __restrict__ qb1,
    const float* __restrict__ kw1, const float* __restrict__ kb1,
    const float* __restrict__ vw1, const float* __restrict__ vb1,
    const float* __restrict__ ar1, const float* __restrict__ mr1,
    const float* __restrict__ p1,
    float* __restrict__ Wf, float* __restrict__ bfv) {
  int gidx = blockIdx.x * 256 + threadIdx.x;
  if (gidx >= 2 * FUSE_T) return;
  int type = gidx >= FUSE_T;
  int idx = gidx - type * FUSE_T;
  const float* qw = type ? qw1 : qw0; const float* qb = type ? qb1 : qb0;
  const float* kw = type ? kw1 : kw0; const float* kb = type ? kb1 : kb0;
  const float* vw = type ? vw1 : vw0; const float* vb = type ? vb1 : vb0;
  const float* ar = type ? ar1 : ar0; const float* mr = type ? mr1 : mr0;
  const float* p  = type ? p1  : p0;
  float* W = Wf + (size_t)type * 64 * 192;
  float* B = bfv + (size_t)type * 192;
  if (idx < 64 * 192) {
    int i = idx / 192, c = idx % 192;
    float o;
    if (c < 64) {
      o = qw[i * 64 + c];
    } else {
      int e = c & 63, hd = e >> 5, ee = e & 31;
      bool isK = c < 128;
      const float* M = isK ? ar : mr;
      const float* Wsrc = isK ? kw : vw;
      float s = 0.0f;
      #pragma unroll
      for (int d = 0; d < 32; ++d)
        s += Wsrc[i * 64 + hd * 32 + d] * M[hd * 32 * 32 + d * 32 + ee];
      if (isK) s *= p[hd] * 0.17677669529663687f;
      o = s;
    }
    W[i * 192 + c] = o;
  } else {
    int c = idx - 64 * 192;
    float o;
    if (c < 64) {
      o = qb[c];
    } else {
      int e = c & 63, hd = e >> 5, ee = e & 31;
      bool isK = c < 128;
      const float* M = isK ? ar : mr;
      const float* Bb = isK ? kb : vb;
      float s = 0.0f;
      #pragma unroll
      for (int d = 0; d < 32; ++d)
        s += Bb[hd * 32 + d] * M[hd * 32 * 32 + d * 32 + ee];
      if (isK) s *= p[hd] * 0.17677669529663687f;
      o = s;
    }
    B[c] = o;
  }
}

// [200k x 192] = h @ Wf[type] + bf[type]; 64-row tiles; q->bf16, kt|vt->packed u32
__global__ __launch_bounds__(256) void k_kqv2(
    const float* __restrict__ h, const float* __restrict__ Wf,
    const float* __restrict__ bfv,
    u16* __restrict__ qo, u32* __restrict__ kvt) {
  __shared__ float ws_[64 * 192];
  __shared__ float hs[64][65];
  int t = threadIdx.x;
  int b = blockIdx.x;
  int type = b >= KQV_BLKS;
  int r0   = type ? (NN + (b - KQV_BLKS) * 64) : (b * 64);
  int rend = type ? NN2 : NN;
  const float* W = Wf + (size_t)type * 64 * 192;
  const float* B = bfv + (size_t)type * 192;
  for (int i = t; i < 64 * 192 / 4; i += 256)
    ((float4*)ws_)[i] = ((const float4*)W)[i];
  for (int i = t; i < 64 * 16; i += 256) {
    int row = i >> 4, c4 = i & 15;
    int gr = r0 + row; if (gr >= rend) gr = rend - 1;
    float4 v = *(const float4*)&h[(size_t)gr * 64 + c4 * 4];
    hs[row][c4 * 4 + 0] = v.x; hs[row][c4 * 4 + 1] = v.y;
    hs[row][c4 * 4 + 2] = v.z; hs[row][c4 * 4 + 3] = v.w;
  }
  __syncthreads();
  int rg = t & 15, cg = t >> 4;
  float acc[3][4][4];
  #pragma unroll
  for (int j = 0; j < 3; j++) {
    #pragma unroll
    for (int c = 0; c < 4; c++) {
      float bv = B[j * 64 + cg * 4 + c];
      #pragma unroll
      for (int r = 0; r < 4; r++) acc[j][r][c] = bv;
    }
  }
  for (int k = 0; k < 64; ++k) {
    float a0 = hs[rg * 4 + 0][k];
    float a1 = hs[rg * 4 + 1][k];
    float a2 = hs[rg * 4 + 2][k];
    float a3 = hs[rg * 4 + 3][k];
    #pragma unroll
    for (int j = 0; j < 3; j++) {
      float4 w = *(const float4*)&ws_[k * 192 + j * 64 + cg * 4];
      acc[j][0][0] = fmaf(a0, w.x, acc[j][0][0]);
      acc[j][0][1] = fmaf(a0, w.y, acc[j][0][1]);
      acc[j][0][2] = fmaf(a0, w.z, acc[j][0][2]);
      acc[j][0][3] = fmaf(a0, w.w, acc[j][0][3]);
      acc[j][1][0] = fmaf(a1, w.x, acc[j][1][0]);
      acc[j][1][1] = fmaf(a1, w.y, acc[j][1][1]);
      acc[j][1][2] = fmaf(a1, w.z, acc[j][1][2]);
      acc[j][1][3] = fmaf(a1, w.w, acc[j][1][3]);
      acc[j][2][0] = fmaf(a2, w.x, acc[j][2][0]);
      acc[j][2][1] = fmaf(a2, w.y, acc[j][2][1]);
      acc[j][2][2] = fmaf(a2, w.z, acc[j][2][2]);
      acc[j][2][3] = fmaf(a2, w.w, acc[j][2][3]);
      acc[j][3][0] = fmaf(a3, w.x, acc[j][3][0]);
      acc[j][3][1] = fmaf(a3, w.y, acc[j][3][1]);
      acc[j][3][2] = fmaf(a3, w.z, acc[j][3][2]);
      acc[j][3][3] = fmaf(a3, w.w, acc[j][3][3]);
    }
  }
  #pragma unroll
  for (int r = 0; r < 4; ++r) {
    int gr = r0 + rg * 4 + r;
    if (gr >= rend) break;
    u32 q0 = (u32)f2bf(acc[0][r][0]) | ((u32)f2bf(acc[0][r][1]) << 16);
    u32 q1 = (u32)f2bf(acc[0][r][2]) | ((u32)f2bf(acc[0][r][3]) << 16);
    *(u32*)&qo[(size_t)gr * 64 + cg * 4]     = q0;
    *(u32*)&qo[(size_t)gr * 64 + cg * 4 + 2] = q1;
    #pragma unroll
    for (int c = 0; c < 4; ++c) {
      u32 kv = (u32)f2bf(acc[1][r][c]) | ((u32)f2bf(acc[2][r][c]) << 16);
      kvt[(size_t)gr * 64 + cg * 4 + c] = kv;
    }
  }
}

// out = LN(sig(skip)*(gelu(agg)@Ow+Ob) + (1-sig(skip))*h + h); 50000 blocks
__global__ __launch_bounds__(256) void k_out(
    const float* __restrict__ agg, const float* __restrict__ h,
    const float* __restrict__ ow0, const float* __restrict__ ob0,
    const float* __restrict__ skip0,
    const float* __restrict__ ow1, const float* __restrict__ ob1,
    const float* __restrict__ skip1,
    const float* __restrict__ lg, const float* __restrict__ lb,
    float* __restrict__ y) {
  __shared__ float ows[HIDC * HIDC];
  __shared__ float gs[4][HIDC];
  int tid = threadIdx.x, wp = tid >> 6, ln = tid & 63;
  int row = blockIdx.x * 4 + wp;
  int type = (blockIdx.x * 4) >= NN;
  const float* ow = type ? ow1 : ow0;
  const float* ob = type ? ob1 : ob0;
  const float* skip = type ? skip1 : skip0;
  for (int i = tid; i < HIDC * HIDC / 4; i += 256)
    ((float4*)ows)[i] = ((const float4*)ow)[i];
  float av = agg[(size_t)row * HIDC + ln];
  float hv = h[(size_t)row * HIDC + ln];
  float ga = 0.5f * av * (1.0f + erff(av * 0.70710678118654752f));
  gs[wp][ln] = ga;
  __syncthreads();
  float a = ob[ln];
  #pragma unroll 8
  for (int i = 0; i < HIDC; i++) a = fmaf(gs[wp][i], ows[i * HIDC + ln], a);
  float g = 1.0f / (1.0f + expf(-skip[0]));
  float t = g * a + (1.0f - g) * hv + hv;
  float mu = wsum(t) * (1.0f / HIDC);
  float d = t - mu;
  float var = wsum(d * d) * (1.0f / HIDC);
  y[(size_t)row * HIDC + ln] = lg[ln] * d * rsqrtf(var + 1e-5f) + lb[ln];
}

// ---------- joint CSR build over global dst ids (200k nodes, 2M edges) ----------

__global__ __launch_bounds__(SCAN_BS) void k_zero(u32* __restrict__ cnt) {
  int i = blockIdx.x * SCAN_BS + threadIdx.x;
  if (i < NN2) cnt[i] = 0;
}

__global__ __launch_bounds__(256) void k_hist(
    const int* __restrict__ ei_m2b, const int* __restrict__ ei_b2m,
    u32* __restrict__ cnt) {
  int e = blockIdx.x * 256 + threadIdx.x;
  if (e < NE) {
    atomicAdd(&cnt[NN + ei_m2b[NE + e]], 1u);        // dst buf -> +NN
  } else if (e < 2 * NE) {
    atomicAdd(&cnt[ei_b2m[NE + (e - NE)]], 1u);      // dst mac
  }
}

__global__ __launch_bounds__(SCAN_BS) void k_scan1(
    const u32* __restrict__ cnt, u32* __restrict__ excl, u32* __restrict__ partials) {
  __shared__ u32 tmp[SCAN_BS];
  int t = threadIdx.x;
  int i = blockIdx.x * SCAN_BS + t;
  u32 v = (i < NN2) ? cnt[i] : 0u;
  tmp[t] = v;
  __syncthreads();
  for (int off = 1; off < SCAN_BS; off <<= 1) {
    u32 add = (t >= off) ? tmp[t - off] : 0u;
    __syncthreads();
    tmp[t] += add;
    __syncthreads();
  }
  if (i < NN2) excl[i] = tmp[t] - v;
  if (t == SCAN_BS - 1) partials[blockIdx.x] = tmp[t];
}

__global__ __launch_bounds__(256) void k_scan2(u32* __restrict__ partials) {
  __shared__ u32 t[NBLK2];
  int i = threadIdx.x;
  if (i < NBLK2) t[i] = partials[i];
  __syncthreads();
  if (i == 0) {
    u32 run = 0;
    for (int j = 0; j < NBLK2; ++j) { u32 v = t[j]; t[j] = run; run += v; }
  }
  __syncthreads();
  if (i < NBLK2) partials[i] = t[i];
}

__global__ __launch_bounds__(SCAN_BS) void k_scan3(
    const u32* __restrict__ excl, const u32* __restrict__ partials,
    u32* __restrict__ rowptr, u32* __restrict__ cursor) {
  int i = blockIdx.x * SCAN_BS + threadIdx.x;
  if (i < NN2) {
    u32 v = excl[i] + partials[blockIdx.x];
    rowptr[i] = v;
    cursor[i] = v;
  }
  if (i == 0) rowptr[NN2] = 2 * NE;
}

__global__ __launch_bounds__(256) void k_scatter(
    const int* __restrict__ ei_m2b, const int* __restrict__ ei_b2m,
    u32* __restrict__ cursor, int* __restrict__ csr_src) {
  int e = blockIdx.x * 256 + threadIdx.x;
  int src_g, dst_g;
  if (e < NE) {
    src_g = ei_m2b[e]; dst_g = NN + ei_m2b[NE + e];
  } else if (e < 2 * NE) {
    int e2 = e - NE;
    src_g = NN + ei_b2m[e2]; dst_g = ei_b2m[NE + e2];
  } else return;
  u32 pos = atomicAdd(&cursor[dst_g], 1u);
  csr_src[pos] = src_g;
}

// ---------- fused edge phase: 4x16-lane groups, 4 edges in flight per wave ----------
__global__ __launch_bounds__(256) void k_edge(
    const u32* __restrict__ rowptr, const int* __restrict__ csr,
    const u16* __restrict__ q, const u32* __restrict__ kvt,
    float* __restrict__ agg) {
  int wid = (blockIdx.x << 2) + (threadIdx.x >> 6);  // dst node (global)
  int ln = threadIdx.x & 63;
  int g = ln >> 4, t = ln & 15;
  // q elems 4t..4t+3 (bf16)
  uint2 qp = *(const uint2*)&q[(size_t)wid * 64 + t * 4];
  float q0 = bf2f(qp.x & 0xFFFFu), q1 = bf2f(qp.x >> 16);
  float q2 = bf2f(qp.y & 0xFFFFu), q3 = bf2f(qp.y >> 16);
  u32 j0 = rowptr[wid], j1 = rowptr[wid + 1];
  float m = -1e30f, s = 0.0f;
  float a0 = 0.0f, a1 = 0.0f, a2 = 0.0f, a3 = 0.0f;
  for (u32 j = j0 + g; j < j1; j += 4) {
    int src = csr[j];
    uint4 w = *(const uint4*)&kvt[(size_t)src * 64 + t * 4];
    float k0 = bf2f(w.x & 0xFFFFu), v0 = bf2f(w.x >> 16);
    float k1 = bf2f(w.y & 0xFFFFu), v1 = bf2f(w.y >> 16);
    float k2 = bf2f(w.z & 0xFFFFu), v2 = bf2f(w.z >> 16);
    float k3 = bf2f(w.w & 0xFFFFu), v3 = bf2f(w.w >> 16);
    float prod = fmaf(q3, k3, fmaf(q2, k2, fmaf(q1, k1, q0 * k0)));
    prod += __shfl_xor(prod, 1, 64);
    prod += __shfl_xor(prod, 2, 64);
    prod += __shfl_xor(prod, 4, 64);   // head-dot in each 8-lane half-group
    float mn = fmaxf(m, prod);
    float c = __expf(m - mn);
    float we = __expf(prod - mn);
    s = fmaf(s, c, we);
    a0 = fmaf(a0, c, we * v0);
    a1 = fmaf(a1, c, we * v1);
    a2 = fmaf(a2, c, we * v2);
    a3 = fmaf(a3, c, we * v3);
    m = mn;
  }
  // merge the 4 group states (butterfly over lane xor 16, 32)
  #pragma unroll
  for (int off = 16; off <= 32; off <<= 1) {
    float om = __shfl_xor(m, off, 64);
    float os = __shfl_xor(s, off, 64);
    float o0 = __shfl_xor(a0, off, 64);
    float o1 = __shfl_xor(a1, off, 64);
    float o2 = __shfl_xor(a2, off, 64);
    float o3 = __shfl_xor(a3, off, 64);
    float mn = fmaxf(m, om);
    float c1 = __expf(m - mn), c2 = __expf(om - mn);
    s = s * c1 + os * c2;
    a0 = a0 * c1 + o0 * c2;
    a1 = a1 * c1 + o1 * c2;
    a2 = a2 * c1 + o2 * c2;
    a3 = a3 * c1 + o3 * c2;
    m = mn;
  }
  if (g == 0) {
    float inv = 1.0f / (s + 1e-16f);
    float4 o = { a0 * inv, a1 * inv, a2 * inv, a3 * inv };
    *(float4*)&agg[(size_t)wid * 64 + t * 4] = o;
  }
}

// ---------- launch ----------
extern "C" void kernel_launch(void* const* d_in, const int* in_sizes, int n_in,
                              void* d_out, int out_size, void* d_ws, size_t ws_size,
                              hipStream_t stream) {
  const float* x_mac     = (const float*)d_in[0];
  const float* x_buf     = (const float*)d_in[1];
  const int*   ei_m2b    = (const int*)d_in[2];
  const int*   ei_b2m    = (const int*)d_in[3];
  const float* enc_w_mac = (const float*)d_in[4];
  const float* enc_b_mac = (const float*)d_in[5];
  const float* enc_g_mac = (const float*)d_in[6];
  const float* enc_be_mac= (const float*)d_in[7];
  const float* k_w_mac   = (const float*)d_in[8];
  const float* k_b_mac   = (const float*)d_in[9];
  const float* q_w_mac   = (const float*)d_in[10];
  const float* q_b_mac   = (const float*)d_in[11];
  const float* v_w_mac   = (const float*)d_in[12];
  const float* v_b_mac   = (const float*)d_in[13];
  const float* o_w_mac   = (const float*)d_in[14];
  const float* o_b_mac   = (const float*)d_in[15];
  const float* skip_mac  = (const float*)d_in[16];
  const float* enc_w_buf = (const float*)d_in[17];
  const float* enc_b_buf = (const float*)d_in[18];
  const float* enc_g_buf = (const float*)d_in[19];
  const float* enc_be_buf= (const float*)d_in[20];
  const float* k_w_buf   = (const float*)d_in[21];
  const float* k_b_buf   = (const float*)d_in[22];
  const float* q_w_buf   = (const float*)d_in[23];
  const float* q_b_buf   = (const float*)d_in[24];
  const float* v_w_buf   = (const float*)d_in[25];
  const float* v_b_buf   = (const float*)d_in[26];
  const float* o_w_buf   = (const float*)d_in[27];
  const float* o_b_buf   = (const float*)d_in[28];
  const float* skip_buf  = (const float*)d_in[29];
  const float* a_m2b     = (const float*)d_in[30];
  const float* m_m2b     = (const float*)d_in[31];
  const float* p_m2b     = (const float*)d_in[32];
  const float* a_b2m     = (const float*)d_in[33];
  const float* m_b2m     = (const float*)d_in[34];
  const float* p_b2m     = (const float*)d_in[35];
  const float* ln_g      = (const float*)d_in[36];
  const float* ln_b      = (const float*)d_in[37];

  char* ws = (char*)d_ws;
  size_t off = 0;
  auto take = [&](size_t bytes) -> char* {
    char* p = ws + off;
    off = (off + bytes + 255) & ~(size_t)255;
    return p;
  };
  float* h       = (float*)take((size_t)NN2 * HIDC * 4);
  float* agg     = (float*)take((size_t)NN2 * HIDC * 4);
  u16*   q       = (u16*)take((size_t)NN2 * HIDC * 2);
  u32*   kvt     = (u32*)take((size_t)NN2 * HIDC * 4);
  float* Wf      = (float*)take((size_t)2 * 64 * 192 * 4);
  float* bfv     = (float*)take((size_t)2 * 192 * 4);
  u32*   cnt     = (u32*)take((size_t)NN2 * 4);
  u32*   excl    = (u32*)take((size_t)NN2 * 4);
  u32*   parts   = (u32*)take((size_t)NBLK2 * 4);
  u32*   rowptr  = (u32*)take((size_t)(NN2 + 1) * 4);
  u32*   cursor  = (u32*)take((size_t)NN2 * 4);
  int*   csr_src = (int*)take((size_t)2 * NE * 4);

  const int node_grid  = NN2 / 4;                   // 50000
  const int edge2_grid = (2 * NE + 255) / 256;      // 7813
  const int fuse_grid  = (2 * FUSE_T + 255) / 256;  // 98

  // CSR build first (independent of node pipeline)
  k_zero<<<NBLK2, SCAN_BS, 0, stream>>>(cnt);
  k_hist<<<edge2_grid, 256, 0, stream>>>(ei_m2b, ei_b2m, cnt);
  k_fuse<<<fuse_grid, 256, 0, stream>>>(
      q_w_mac, q_b_mac, k_w_mac, k_b_mac, v_w_mac, v_b_mac, a_m2b, m_m2b, p_m2b,
      q_w_buf, q_b_buf, k_w_buf, k_b_buf, v_w_buf, v_b_buf, a_b2m, m_b2m, p_b2m,
      Wf, bfv);
  k_enc<<<node_grid, 256, 0, stream>>>(
      x_mac, x_buf,
      enc_w_mac, enc_b_mac, enc_g_mac, enc_be_mac,
      enc_w_buf, enc_b_buf, enc_g_buf, enc_be_buf, h);
  k_scan1<<<NBLK2, SCAN_BS, 0, stream>>>(cnt, excl, parts);
  k_scan2<<<1, 256, 0, stream>>>(parts);
  k_scan3<<<NBLK2, SCAN_BS, 0, stream>>>(excl, parts, rowptr, cursor);
  k_scatter<<<edge2_grid, 256, 0, stream>>>(ei_m2b, ei_b2m, cursor, csr_src);
  k_kqv2<<<2 * KQV_BLKS, 256, 0, stream>>>(h, Wf, bfv, q, kvt);
  k_edge<<<node_grid, 256, 0, stream>>>(rowptr, csr_src, q, kvt, agg);
  k_out<<<node_grid, 256, 0, stream>>>(
      agg, h, o_w_mac, o_b_mac, skip_mac, o_w_buf, o_b_buf, skip_buf,
      ln_g, ln_b, (float*)d_out);
}

// Round 5
// 421.472 us; speedup vs baseline: 19.1196x; 1.4287x over previous
//
#include <hip/hip_runtime.h>
#include <hip/hip_bf16.h>
#include <math.h>

#define NN 100000
#define NN2 200000
#define NE 1000000
#define FIN 32
#define HIDC 64

#define NB 782            // ceil(NN2/256) buckets of 256 dsts
#define NBP 1024          // padded
#define EPB 4096          // edges per scatter/hist block
#define SCGRID 489        // ceil(2*NE / EPB)
#define CAP 3072          // max edges per bucket (mean 2560, sigma~51)
#define KQV_BLKS 1563     // ceil(NN/64)

typedef unsigned int u32;
typedef unsigned short u16;

// ---------- helpers ----------
__device__ __forceinline__ float wsum(float v) {
  #pragma unroll
  for (int off = 32; off; off >>= 1) v += __shfl_xor(v, off, 64);
  return v;
}

__device__ __forceinline__ u16 f2bf(float f) {
  union { float f; u32 u; } c; c.f = f;
  u32 u = c.u;
  return (u16)((u + 0x7FFFu + ((u >> 16) & 1u)) >> 16);
}

__device__ __forceinline__ float bf2f(u32 v) {  // low 16 bits = bf16
  union { u32 u; float f; } c; c.u = v << 16; return c.f;
}

// in-place exclusive scan of a[1024] by 256 threads (4 entries/thread)
__device__ __forceinline__ void scan1024(u32* a, u32* wtot) {
  int t = threadIdx.x, lane = t & 63, wv = t >> 6;
  u32 v0 = a[t * 4 + 0], v1 = a[t * 4 + 1], v2 = a[t * 4 + 2], v3 = a[t * 4 + 3];
  u32 sum = v0 + v1 + v2 + v3;
  u32 x = sum;
  #pragma unroll
  for (int off = 1; off < 64; off <<= 1) {
    u32 y = __shfl_up(x, off, 64);
    if (lane >= off) x += y;
  }
  if (lane == 63) wtot[wv] = x;
  u32 excl = x - sum;
  __syncthreads();
  u32 wb = 0;
  #pragma unroll
  for (int w = 0; w < 4; w++) if (w < wv) wb += wtot[w];
  u32 b = wb + excl;
  a[t * 4 + 0] = b;
  a[t * 4 + 1] = b + v0;
  a[t * 4 + 2] = b + v0 + v1;
  a[t * 4 + 3] = b + v0 + v1 + v2;
}

// decode edge ee in [0, 2*NE) -> global src, dst
__device__ __forceinline__ void edge_decode(
    int ee, const int* __restrict__ ei_m2b, const int* __restrict__ ei_b2m,
    int& src_g, int& dst_g) {
  if (ee < NE) {
    src_g = ei_m2b[ee];
    dst_g = NN + ei_m2b[NE + ee];
  } else {
    int e2 = ee - NE;
    src_g = NN + ei_b2m[e2];
    dst_g = ei_b2m[NE + e2];
  }
}

// ---------- node kernels ----------

__global__ __launch_bounds__(256) void k_enc(
    const float* __restrict__ x_mac, const float* __restrict__ x_buf,
    const float* __restrict__ w_mac, const float* __restrict__ b_mac,
    const float* __restrict__ g_mac, const float* __restrict__ be_mac,
    const float* __restrict__ w_buf, const float* __restrict__ b_buf,
    const float* __restrict__ g_buf, const float* __restrict__ be_buf,
    float* __restrict__ h) {
  __shared__ float ws_[FIN * HIDC];
  __shared__ float xs[4][FIN];
  int tid = threadIdx.x;
  int wp = tid >> 6, ln = tid & 63;
  int row = blockIdx.x * 4 + wp;
  int type = (blockIdx.x * 4) >= NN;
  const float* w  = type ? w_buf  : w_mac;
  const float* b  = type ? b_buf  : b_mac;
  const float* g  = type ? g_buf  : g_mac;
  const float* be = type ? be_buf : be_mac;
  const float* x  = type ? (x_buf - (size_t)NN * FIN) : x_mac;
  for (int i = tid; i < FIN * HIDC; i += 256) ws_[i] = w[i];
  if (ln < FIN) xs[wp][ln] = x[(size_t)row * FIN + ln];
  __syncthreads();
  float acc = b[ln];
  #pragma unroll
  for (int i = 0; i < FIN; i++) acc = fmaf(xs[wp][i], ws_[i * HIDC + ln], acc);
  float mu = wsum(acc) * (1.0f / HIDC);
  float d = acc - mu;
  float var = wsum(d * d) * (1.0f / HIDC);
  float y = g[ln] * d * rsqrtf(var + 1e-5f) + be[ln];
  h[(size_t)row * HIDC + ln] = fmaxf(y, 0.0f);
}

#define FUSE_T (64 * 192 + 192)
__global__ __launch_bounds__(256) void k_fuse(
    const float* __restrict__ qw0, const float* __restrict__ qb0,
    const float* __restrict__ kw0, const float* __restrict__ kb0,
    const float* __restrict__ vw0, const float* __restrict__ vb0,
    const float* __restrict__ ar0, const float* __restrict__ mr0,
    const float* __restrict__ p0,
    const float* __restrict__ qw1, const float* __restrict__ qb1,
    const float* __restrict__ kw1, const float* __restrict__ kb1,
    const float* __restrict__ vw1, const float* __restrict__ vb1,
    const float* __restrict__ ar1, const float* __restrict__ mr1,
    const float* __restrict__ p1,
    float* __restrict__ Wf, float* __restrict__ bfv) {
  int gidx = blockIdx.x * 256 + threadIdx.x;
  if (gidx >= 2 * FUSE_T) return;
  int type = gidx >= FUSE_T;
  int idx = gidx - type * FUSE_T;
  const float* qw = type ? qw1 : qw0; const float* qb = type ? qb1 : qb0;
  const float* kw = type ? kw1 : kw0; const float* kb = type ? kb1 : kb0;
  const float* vw = type ? vw1 : vw0; const float* vb = type ? vb1 : vb0;
  const float* ar = type ? ar1 : ar0; const float* mr = type ? mr1 : mr0;
  const float* p  = type ? p1  : p0;
  float* W = Wf + (size_t)type * 64 * 192;
  float* B = bfv + (size_t)type * 192;
  if (idx < 64 * 192) {
    int i = idx / 192, c = idx % 192;
    float o;
    if (c < 64) {
      o = qw[i * 64 + c];
    } else {
      int e = c & 63, hd = e >> 5, ee = e & 31;
      bool isK = c < 128;
      const float* M = isK ? ar : mr;
      const float* Wsrc = isK ? kw : vw;
      float s = 0.0f;
      #pragma unroll
      for (int d = 0; d < 32; ++d)
        s += Wsrc[i * 64 + hd * 32 + d] * M[hd * 32 * 32 + d * 32 + ee];
      if (isK) s *= p[hd] * 0.17677669529663687f;
      o = s;
    }
    W[i * 192 + c] = o;
  } else {
    int c = idx - 64 * 192;
    float o;
    if (c < 64) {
      o = qb[c];
    } else {
      int e = c & 63, hd = e >> 5, ee = e & 31;
      bool isK = c < 128;
      const float* M = isK ? ar : mr;
      const float* Bb = isK ? kb : vb;
      float s = 0.0f;
      #pragma unroll
      for (int d = 0; d < 32; ++d)
        s += Bb[hd * 32 + d] * M[hd * 32 * 32 + d * 32 + ee];
      if (isK) s *= p[hd] * 0.17677669529663687f;
      o = s;
    }
    B[c] = o;
  }
}

__global__ __launch_bounds__(256) void k_kqv2(
    const float* __restrict__ h, const float* __restrict__ Wf,
    const float* __restrict__ bfv,
    u16* __restrict__ qo, u32* __restrict__ kvt) {
  __shared__ float ws_[64 * 192];
  __shared__ float hs[64][65];
  int t = threadIdx.x;
  int b = blockIdx.x;
  int type = b >= KQV_BLKS;
  int r0   = type ? (NN + (b - KQV_BLKS) * 64) : (b * 64);
  int rend = type ? NN2 : NN;
  const float* W = Wf + (size_t)type * 64 * 192;
  const float* B = bfv + (size_t)type * 192;
  for (int i = t; i < 64 * 192 / 4; i += 256)
    ((float4*)ws_)[i] = ((const float4*)W)[i];
  for (int i = t; i < 64 * 16; i += 256) {
    int row = i >> 4, c4 = i & 15;
    int gr = r0 + row; if (gr >= rend) gr = rend - 1;
    float4 v = *(const float4*)&h[(size_t)gr * 64 + c4 * 4];
    hs[row][c4 * 4 + 0] = v.x; hs[row][c4 * 4 + 1] = v.y;
    hs[row][c4 * 4 + 2] = v.z; hs[row][c4 * 4 + 3] = v.w;
  }
  __syncthreads();
  int rg = t & 15, cg = t >> 4;
  float acc[3][4][4];
  #pragma unroll
  for (int j = 0; j < 3; j++) {
    #pragma unroll
    for (int c = 0; c < 4; c++) {
      float bv = B[j * 64 + cg * 4 + c];
      #pragma unroll
      for (int r = 0; r < 4; r++) acc[j][r][c] = bv;
    }
  }
  for (int k = 0; k < 64; ++k) {
    float a0 = hs[rg * 4 + 0][k];
    float a1 = hs[rg * 4 + 1][k];
    float a2 = hs[rg * 4 + 2][k];
    float a3 = hs[rg * 4 + 3][k];
    #pragma unroll
    for (int j = 0; j < 3; j++) {
      float4 w = *(const float4*)&ws_[k * 192 + j * 64 + cg * 4];
      acc[j][0][0] = fmaf(a0, w.x, acc[j][0][0]);
      acc[j][0][1] = fmaf(a0, w.y, acc[j][0][1]);
      acc[j][0][2] = fmaf(a0, w.z, acc[j][0][2]);
      acc[j][0][3] = fmaf(a0, w.w, acc[j][0][3]);
      acc[j][1][0] = fmaf(a1, w.x, acc[j][1][0]);
      acc[j][1][1] = fmaf(a1, w.y, acc[j][1][1]);
      acc[j][1][2] = fmaf(a1, w.z, acc[j][1][2]);
      acc[j][1][3] = fmaf(a1, w.w, acc[j][1][3]);
      acc[j][2][0] = fmaf(a2, w.x, acc[j][2][0]);
      acc[j][2][1] = fmaf(a2, w.y, acc[j][2][1]);
      acc[j][2][2] = fmaf(a2, w.z, acc[j][2][2]);
      acc[j][2][3] = fmaf(a2, w.w, acc[j][2][3]);
      acc[j][3][0] = fmaf(a3, w.x, acc[j][3][0]);
      acc[j][3][1] = fmaf(a3, w.y, acc[j][3][1]);
      acc[j][3][2] = fmaf(a3, w.z, acc[j][3][2]);
      acc[j][3][3] = fmaf(a3, w.w, acc[j][3][3]);
    }
  }
  #pragma unroll
  for (int r = 0; r < 4; ++r) {
    int gr = r0 + rg * 4 + r;
    if (gr >= rend) break;
    u32 q0 = (u32)f2bf(acc[0][r][0]) | ((u32)f2bf(acc[0][r][1]) << 16);
    u32 q1 = (u32)f2bf(acc[0][r][2]) | ((u32)f2bf(acc[0][r][3]) << 16);
    *(u32*)&qo[(size_t)gr * 64 + cg * 4]     = q0;
    *(u32*)&qo[(size_t)gr * 64 + cg * 4 + 2] = q1;
    #pragma unroll
    for (int c = 0; c < 4; ++c) {
      u32 kv = (u32)f2bf(acc[1][r][c]) | ((u32)f2bf(acc[2][r][c]) << 16);
      kvt[(size_t)gr * 64 + cg * 4 + c] = kv;
    }
  }
}

__global__ __launch_bounds__(256) void k_out(
    const float* __restrict__ agg, const float* __restrict__ h,
    const float* __restrict__ ow0, const float* __restrict__ ob0,
    const float* __restrict__ skip0,
    const float* __restrict__ ow1, const float* __restrict__ ob1,
    const float* __restrict__ skip1,
    const float* __restrict__ lg, const float* __restrict__ lb,
    float* __restrict__ y) {
  __shared__ float ows[HIDC * HIDC];
  __shared__ float gs[4][HIDC];
  int tid = threadIdx.x, wp = tid >> 6, ln = tid & 63;
  int row = blockIdx.x * 4 + wp;
  int type = (blockIdx.x * 4) >= NN;
  const float* ow = type ? ow1 : ow0;
  const float* ob = type ? ob1 : ob0;
  const float* skip = type ? skip1 : skip0;
  for (int i = tid; i < HIDC * HIDC / 4; i += 256)
    ((float4*)ows)[i] = ((const float4*)ow)[i];
  float av = agg[(size_t)row * HIDC + ln];
  float hv = h[(size_t)row * HIDC + ln];
  float ga = 0.5f * av * (1.0f + erff(av * 0.70710678118654752f));
  gs[wp][ln] = ga;
  __syncthreads();
  float a = ob[ln];
  #pragma unroll 8
  for (int i = 0; i < HIDC; i++) a = fmaf(gs[wp][i], ows[i * HIDC + ln], a);
  float g = 1.0f / (1.0f + expf(-skip[0]));
  float t = g * a + (1.0f - g) * hv + hv;
  float mu = wsum(t) * (1.0f / HIDC);
  float d = t - mu;
  float var = wsum(d * d) * (1.0f / HIDC);
  y[(size_t)row * HIDC + ln] = lg[ln] * d * rsqrtf(var + 1e-5f) + lb[ln];
}

// ---------- bucketed edge pipeline ----------

__global__ __launch_bounds__(256) void k_gzero(u32* __restrict__ gh) {
  int i = blockIdx.x * 256 + threadIdx.x;
  if (i < NBP) gh[i] = 0;
}

// per-block LDS bucket histogram -> coalesced global atomics
__global__ __launch_bounds__(256) void k_bhist(
    const int* __restrict__ ei_m2b, const int* __restrict__ ei_b2m,
    u32* __restrict__ gh) {
  __shared__ u32 hist[NBP];
  int tid = threadIdx.x;
  for (int i = tid; i < NBP; i += 256) hist[i] = 0;
  __syncthreads();
  int base_e = blockIdx.x * EPB;
  #pragma unroll
  for (int i = 0; i < EPB / 256; i++) {
    int ee = base_e + i * 256 + tid;
    if (ee < 2 * NE) {
      int src_g, dst_g;
      edge_decode(ee, ei_m2b, ei_b2m, src_g, dst_g);
      atomicAdd(&hist[dst_g >> 8], 1u);
    }
  }
  __syncthreads();
  for (int b = tid; b < NBP; b += 256) {
    u32 c = hist[b];
    if (c) atomicAdd(&gh[b], c);
  }
}

// scan bucket counts -> bstart[NB+1], gcursor init
__global__ __launch_bounds__(256) void k_bscan(
    const u32* __restrict__ gh, u32* __restrict__ bstart, u32* __restrict__ gcursor) {
  __shared__ u32 a[NBP];
  __shared__ u32 wtot[4];
  int t = threadIdx.x;
  for (int i = t; i < NBP; i += 256) a[i] = (i < NB) ? gh[i] : 0u;
  __syncthreads();
  scan1024(a, wtot);
  __syncthreads();
  for (int i = t; i < NB; i += 256) { bstart[i] = a[i]; gcursor[i] = a[i]; }
  if (t == 0) bstart[NB] = 2 * NE;
}

// grouped scatter: pairs (dst&255)<<18 | src into bucket-contiguous regions
__global__ __launch_bounds__(256) void k_bscatter(
    const int* __restrict__ ei_m2b, const int* __restrict__ ei_b2m,
    u32* __restrict__ gcursor, u32* __restrict__ bpairs) {
  __shared__ u32 hist[NBP];
  __shared__ u32 loff[NBP];
  __shared__ u32 gbase[NBP];
  __shared__ u32 wtot[4];
  __shared__ u32 pairs[EPB];
  __shared__ u16 sbuck[EPB];
  int tid = threadIdx.x;
  for (int i = tid; i < NBP; i += 256) hist[i] = 0;
  __syncthreads();
  int base_e = blockIdx.x * EPB;
  u32 pk[EPB / 256];
  u16 bk[EPB / 256];
  u16 rk[EPB / 256];
  #pragma unroll
  for (int i = 0; i < EPB / 256; i++) {
    int ee = base_e + i * 256 + tid;
    if (ee < 2 * NE) {
      int src_g, dst_g;
      edge_decode(ee, ei_m2b, ei_b2m, src_g, dst_g);
      u32 b = (u32)dst_g >> 8;
      pk[i] = ((u32)(dst_g & 255) << 18) | (u32)src_g;
      bk[i] = (u16)b;
      rk[i] = (u16)atomicAdd(&hist[b], 1u);
    } else {
      bk[i] = 0xFFFFu;
    }
  }
  __syncthreads();
  for (int i = tid; i < NBP; i += 256) loff[i] = hist[i];
  __syncthreads();
  scan1024(loff, wtot);
  __syncthreads();
  #pragma unroll
  for (int i = 0; i < EPB / 256; i++) {
    if (bk[i] != 0xFFFFu) {
      u32 s = loff[bk[i]] + rk[i];
      pairs[s] = pk[i];
      sbuck[s] = bk[i];
    }
  }
  __syncthreads();
  for (int b = tid; b < NBP; b += 256) {
    u32 c = hist[b];
    gbase[b] = c ? atomicAdd(&gcursor[b], c) : 0u;
  }
  __syncthreads();
  int nval = 2 * NE - base_e;
  if (nval > EPB) nval = EPB;
  for (int s = tid; s < nval; s += 256) {
    u32 b = sbuck[s];
    bpairs[gbase[b] + (s - loff[b])] = pairs[s];
  }
}

// one block per bucket: LDS counting sort by local dst, then fused
// alpha + online softmax + aggregate with 4x16-lane groups per wave
__global__ __launch_bounds__(512) void k_bedge(
    const u32* __restrict__ bstart, const u32* __restrict__ bpairs,
    const u16* __restrict__ q, const u32* __restrict__ kvt,
    float* __restrict__ agg) {
  __shared__ u32 pairs[CAP];
  __shared__ u32 srt[CAP];
  __shared__ u32 hist[256];     // later reused as scatter cursor
  __shared__ u32 rowptr[257];
  int tid = threadIdx.x;
  int b = blockIdx.x;
  u32 r0 = bstart[b], r1 = bstart[b + 1];
  int n = (int)(r1 - r0);
  if (n > CAP) n = CAP;
  for (int i = tid; i < 256; i += 512) hist[i] = 0;
  __syncthreads();
  for (int i = tid; i < n; i += 512) {
    u32 p = bpairs[r0 + i];
    pairs[i] = p;
    atomicAdd(&hist[p >> 18], 1u);
  }
  __syncthreads();
  if (tid < 64) {
    int lane = tid;
    u32 v0 = hist[tid * 4 + 0], v1 = hist[tid * 4 + 1];
    u32 v2 = hist[tid * 4 + 2], v3 = hist[tid * 4 + 3];
    u32 sum = v0 + v1 + v2 + v3;
    u32 x = sum;
    #pragma unroll
    for (int off = 1; off < 64; off <<= 1) {
      u32 y = __shfl_up(x, off, 64);
      if (lane >= off) x += y;
    }
    u32 base = x - sum;
    rowptr[tid * 4 + 0] = base;
    rowptr[tid * 4 + 1] = base + v0;
    rowptr[tid * 4 + 2] = base + v0 + v1;
    rowptr[tid * 4 + 3] = base + v0 + v1 + v2;
    if (tid == 63) rowptr[256] = x;
  }
  __syncthreads();
  for (int i = tid; i < 256; i += 512) hist[i] = rowptr[i];
  __syncthreads();
  for (int i = tid; i < n; i += 512) {
    u32 p = pairs[i];
    u32 pos = atomicAdd(&hist[p >> 18], 1u);
    srt[pos] = p & 0x3FFFFu;
  }
  __syncthreads();
  int wv = tid >> 6, ln = tid & 63, g = ln >> 4, t = ln & 15;
  for (int d8 = wv; d8 < 256; d8 += 8) {
    int dst_g = (b << 8) + d8;
    if (dst_g >= NN2) break;
    u32 j0 = rowptr[d8], j1 = rowptr[d8 + 1];
    uint2 qp = *(const uint2*)&q[(size_t)dst_g * 64 + t * 4];
    float q0 = bf2f(qp.x & 0xFFFFu), q1 = bf2f(qp.x >> 16);
    float q2 = bf2f(qp.y & 0xFFFFu), q3 = bf2f(qp.y >> 16);
    float m = -1e30f, s = 0.0f;
    float a0 = 0.0f, a1 = 0.0f, a2 = 0.0f, a3 = 0.0f;
    for (u32 j = j0 + g; j < j1; j += 4) {
      u32 src = srt[j];
      uint4 w = *(const uint4*)&kvt[(size_t)src * 64 + t * 4];
      float k0 = bf2f(w.x & 0xFFFFu), v0 = bf2f(w.x >> 16);
      float k1 = bf2f(w.y & 0xFFFFu), v1 = bf2f(w.y >> 16);
      float k2 = bf2f(w.z & 0xFFFFu), v2 = bf2f(w.z >> 16);
      float k3 = bf2f(w.w & 0xFFFFu), v3 = bf2f(w.w >> 16);
      float prod = fmaf(q3, k3, fmaf(q2, k2, fmaf(q1, k1, q0 * k0)));
      prod += __shfl_xor(prod, 1, 64);
      prod += __shfl_xor(prod, 2, 64);
      prod += __shfl_xor(prod, 4, 64);
      float mn = fmaxf(m, prod);
      float c = __expf(m - mn);
      float we = __expf(prod - mn);
      s = fmaf(s, c, we);
      a0 = fmaf(a0, c, we * v0);
      a1 = fmaf(a1, c, we * v1);
      a2 = fmaf(a2, c, we * v2);
      a3 = fmaf(a3, c, we * v3);
      m = mn;
    }
    #pragma unroll
    for (int off = 16; off <= 32; off <<= 1) {
      float om = __shfl_xor(m, off, 64);
      float os = __shfl_xor(s, off, 64);
      float o0 = __shfl_xor(a0, off, 64);
      float o1 = __shfl_xor(a1, off, 64);
      float o2 = __shfl_xor(a2, off, 64);
      float o3 = __shfl_xor(a3, off, 64);
      float mn = fmaxf(m, om);
      float c1 = __expf(m - mn), c2 = __expf(om - mn);
      s = s * c1 + os * c2;
      a0 = a0 * c1 + o0 * c2;
      a1 = a1 * c1 + o1 * c2;
      a2 = a2 * c1 + o2 * c2;
      a3 = a3 * c1 + o3 * c2;
      m = mn;
    }
    if (g == 0) {
      float inv = 1.0f / (s + 1e-16f);
      float4 o = { a0 * inv, a1 * inv, a2 * inv, a3 * inv };
      *(float4*)&agg[(size_t)dst_g * 64 + t * 4] = o;
    }
  }
}

// ---------- launch ----------
extern "C" void kernel_launch(void* const* d_in, const int* in_sizes, int n_in,
                              void* d_out, int out_size, void* d_ws, size_t ws_size,
                              hipStream_t stream) {
  const float* x_mac     = (const float*)d_in[0];
  const float* x_buf     = (const float*)d_in[1];
  const int*   ei_m2b    = (const int*)d_in[2];
  const int*   ei_b2m    = (const int*)d_in[3];
  const float* enc_w_mac = (const float*)d_in[4];
  const float* enc_b_mac = (const float*)d_in[5];
  const float* enc_g_mac = (const float*)d_in[6];
  const float* enc_be_mac= (const float*)d_in[7];
  const float* k_w_mac   = (const float*)d_in[8];
  const float* k_b_mac   = (const float*)d_in[9];
  const float* q_w_mac   = (const float*)d_in[10];
  const float* q_b_mac   = (const float*)d_in[11];
  const float* v_w_mac   = (const float*)d_in[12];
  const float* v_b_mac   = (const float*)d_in[13];
  const float* o_w_mac   = (const float*)d_in[14];
  const float* o_b_mac   = (const float*)d_in[15];
  const float* skip_mac  = (const float*)d_in[16];
  const float* enc_w_buf = (const float*)d_in[17];
  const float* enc_b_buf = (const float*)d_in[18];
  const float* enc_g_buf = (const float*)d_in[19];
  const float* enc_be_buf= (const float*)d_in[20];
  const float* k_w_buf   = (const float*)d_in[21];
  const float* k_b_buf   = (const float*)d_in[22];
  const float* q_w_buf   = (const float*)d_in[23];
  const float* q_b_buf   = (const float*)d_in[24];
  const float* v_w_buf   = (const float*)d_in[25];
  const float* v_b_buf   = (const float*)d_in[26];
  const float* o_w_buf   = (const float*)d_in[27];
  const float* o_b_buf   = (const float*)d_in[28];
  const float* skip_buf  = (const float*)d_in[29];
  const float* a_m2b     = (const float*)d_in[30];
  const float* m_m2b     = (const float*)d_in[31];
  const float* p_m2b     = (const float*)d_in[32];
  const float* a_b2m     = (const float*)d_in[33];
  const float* m_b2m     = (const float*)d_in[34];
  const float* p_b2m     = (const float*)d_in[35];
  const float* ln_g      = (const float*)d_in[36];
  const float* ln_b      = (const float*)d_in[37];

  char* ws = (char*)d_ws;
  size_t off = 0;
  auto take = [&](size_t bytes) -> char* {
    char* p = ws + off;
    off = (off + bytes + 255) & ~(size_t)255;
    return p;
  };
  float* h       = (float*)take((size_t)NN2 * HIDC * 4);
  float* agg     = (float*)take((size_t)NN2 * HIDC * 4);
  u16*   q       = (u16*)take((size_t)NN2 * HIDC * 2);
  u32*   kvt     = (u32*)take((size_t)NN2 * HIDC * 4);
  float* Wf      = (float*)take((size_t)2 * 64 * 192 * 4);
  float* bfv     = (float*)take((size_t)2 * 192 * 4);
  u32*   ghist   = (u32*)take((size_t)NBP * 4);
  u32*   bstart  = (u32*)take((size_t)(NB + 1) * 4);
  u32*   gcursor = (u32*)take((size_t)NBP * 4);
  u32*   bpairs  = (u32*)take((size_t)2 * NE * 4);

  const int node_grid = NN2 / 4;                    // 50000
  const int fuse_grid = (2 * FUSE_T + 255) / 256;   // 98

  k_fuse<<<fuse_grid, 256, 0, stream>>>(
      q_w_mac, q_b_mac, k_w_mac, k_b_mac, v_w_mac, v_b_mac, a_m2b, m_m2b, p_m2b,
      q_w_buf, q_b_buf, k_w_buf, k_b_buf, v_w_buf, v_b_buf, a_b2m, m_b2m, p_b2m,
      Wf, bfv);
  k_gzero<<<(NBP + 255) / 256, 256, 0, stream>>>(ghist);
  k_bhist<<<SCGRID, 256, 0, stream>>>(ei_m2b, ei_b2m, ghist);
  k_enc<<<node_grid, 256, 0, stream>>>(
      x_mac, x_buf,
      enc_w_mac, enc_b_mac, enc_g_mac, enc_be_mac,
      enc_w_buf, enc_b_buf, enc_g_buf, enc_be_buf, h);
  k_bscan<<<1, 256, 0, stream>>>(ghist, bstart, gcursor);
  k_bscatter<<<SCGRID, 256, 0, stream>>>(ei_m2b, ei_b2m, gcursor, bpairs);
  k_kqv2<<<2 * KQV_BLKS, 256, 0, stream>>>(h, Wf, bfv, q, kvt);
  k_bedge<<<NB, 512, 0, stream>>>(bstart, bpairs, q, kvt, agg);
  k_out<<<node_grid, 256, 0, stream>>>(
      agg, h, o_w_mac, o_b_mac, skip_mac, o_w_buf, o_b_buf, skip_buf,
      ln_g, ln_b, (float*)d_out);
}

// Round 6
// 355.330 us; speedup vs baseline: 22.6787x; 1.1861x over previous
//
#include <hip/hip_runtime.h>
#include <hip/hip_bf16.h>
#include <math.h>

#define NN 100000
#define NN2 200000
#define NE 1000000
#define FIN 32
#define HIDC 64

#define NB 782            // ceil(NN2/256) buckets of 256 dsts
#define NBP 1024          // padded
#define EPB 4096          // edges per scatter/hist block
#define SCGRID 489        // ceil(2*NE / EPB)
#define CAP 3072          // max edges per bucket (mean 2560)
#define KQV_BLKS 1563     // ceil(NN/64)

typedef unsigned int u32;
typedef unsigned short u16;

// ---------- helpers ----------
__device__ __forceinline__ float wsum(float v) {
  #pragma unroll
  for (int off = 32; off; off >>= 1) v += __shfl_xor(v, off, 64);
  return v;
}

__device__ __forceinline__ u16 f2bf(float f) {
  union { float f; u32 u; } c; c.f = f;
  u32 u = c.u;
  return (u16)((u + 0x7FFFu + ((u >> 16) & 1u)) >> 16);
}

__device__ __forceinline__ float bf2f(u32 v) {  // low 16 bits = bf16
  union { u32 u; float f; } c; c.u = v << 16; return c.f;
}

// in-place exclusive scan of a[1024] by 256 threads (4 entries/thread)
__device__ __forceinline__ void scan1024(u32* a, u32* wtot) {
  int t = threadIdx.x, lane = t & 63, wv = t >> 6;
  u32 v0 = a[t * 4 + 0], v1 = a[t * 4 + 1], v2 = a[t * 4 + 2], v3 = a[t * 4 + 3];
  u32 sum = v0 + v1 + v2 + v3;
  u32 x = sum;
  #pragma unroll
  for (int off = 1; off < 64; off <<= 1) {
    u32 y = __shfl_up(x, off, 64);
    if (lane >= off) x += y;
  }
  if (lane == 63) wtot[wv] = x;
  u32 excl = x - sum;
  __syncthreads();
  u32 wb = 0;
  #pragma unroll
  for (int w = 0; w < 4; w++) if (w < wv) wb += wtot[w];
  u32 b = wb + excl;
  a[t * 4 + 0] = b;
  a[t * 4 + 1] = b + v0;
  a[t * 4 + 2] = b + v0 + v1;
  a[t * 4 + 3] = b + v0 + v1 + v2;
}

__device__ __forceinline__ void edge_decode(
    int ee, const int* __restrict__ ei_m2b, const int* __restrict__ ei_b2m,
    int& src_g, int& dst_g) {
  if (ee < NE) {
    src_g = ei_m2b[ee];
    dst_g = NN + ei_m2b[NE + ee];
  } else {
    int e2 = ee - NE;
    src_g = NN + ei_b2m[e2];
    dst_g = ei_b2m[NE + e2];
  }
}

// ---------- node kernels (64-row tile GEMMs; mac tiles 0..1562, buf 1563..3125) ----------

// h = relu(LN(x @ W + b)): tile GEMM + LDS LN epilogue
__global__ __launch_bounds__(256) void k_enc2(
    const float* __restrict__ x_mac, const float* __restrict__ x_buf,
    const float* __restrict__ w_mac, const float* __restrict__ b_mac,
    const float* __restrict__ g_mac, const float* __restrict__ be_mac,
    const float* __restrict__ w_buf, const float* __restrict__ b_buf,
    const float* __restrict__ g_buf, const float* __restrict__ be_buf,
    float* __restrict__ h) {
  __shared__ float ws_[FIN * HIDC];        // 8 KB (k-major: w[k][c])
  __shared__ float xs[64][FIN + 1];        // 8.25 KB
  __shared__ float ts[64][HIDC + 1];       // 16.25 KB
  int t = threadIdx.x;
  int b = blockIdx.x;
  int type = b >= KQV_BLKS;
  int r0   = type ? (NN + (b - KQV_BLKS) * 64) : (b * 64);
  int rend = type ? NN2 : NN;
  const float* w  = type ? w_buf  : w_mac;
  const float* bb = type ? b_buf  : b_mac;
  const float* g  = type ? g_buf  : g_mac;
  const float* be = type ? be_buf : be_mac;
  const float* x  = type ? x_buf  : x_mac;
  int xoff = type ? NN : 0;
  for (int i = t; i < FIN * HIDC / 4; i += 256)
    ((float4*)ws_)[i] = ((const float4*)w)[i];
  for (int i = t; i < 64 * 8; i += 256) {
    int row = i >> 3, c4 = i & 7;
    int gr = r0 + row; if (gr >= rend) gr = rend - 1;
    float4 v = *(const float4*)&x[(size_t)(gr - xoff) * FIN + c4 * 4];
    xs[row][c4 * 4 + 0] = v.x; xs[row][c4 * 4 + 1] = v.y;
    xs[row][c4 * 4 + 2] = v.z; xs[row][c4 * 4 + 3] = v.w;
  }
  __syncthreads();
  int rg = t & 15, cg = t >> 4;
  float acc[4][4];
  #pragma unroll
  for (int c = 0; c < 4; c++) {
    float bv = bb[cg * 4 + c];
    #pragma unroll
    for (int r = 0; r < 4; r++) acc[r][c] = bv;
  }
  for (int k = 0; k < FIN; ++k) {
    float a0 = xs[rg * 4 + 0][k];
    float a1 = xs[rg * 4 + 1][k];
    float a2 = xs[rg * 4 + 2][k];
    float a3 = xs[rg * 4 + 3][k];
    float4 wv4 = *(const float4*)&ws_[k * HIDC + cg * 4];
    acc[0][0] = fmaf(a0, wv4.x, acc[0][0]); acc[0][1] = fmaf(a0, wv4.y, acc[0][1]);
    acc[0][2] = fmaf(a0, wv4.z, acc[0][2]); acc[0][3] = fmaf(a0, wv4.w, acc[0][3]);
    acc[1][0] = fmaf(a1, wv4.x, acc[1][0]); acc[1][1] = fmaf(a1, wv4.y, acc[1][1]);
    acc[1][2] = fmaf(a1, wv4.z, acc[1][2]); acc[1][3] = fmaf(a1, wv4.w, acc[1][3]);
    acc[2][0] = fmaf(a2, wv4.x, acc[2][0]); acc[2][1] = fmaf(a2, wv4.y, acc[2][1]);
    acc[2][2] = fmaf(a2, wv4.z, acc[2][2]); acc[2][3] = fmaf(a2, wv4.w, acc[2][3]);
    acc[3][0] = fmaf(a3, wv4.x, acc[3][0]); acc[3][1] = fmaf(a3, wv4.y, acc[3][1]);
    acc[3][2] = fmaf(a3, wv4.z, acc[3][2]); acc[3][3] = fmaf(a3, wv4.w, acc[3][3]);
  }
  #pragma unroll
  for (int r = 0; r < 4; r++)
    #pragma unroll
    for (int c = 0; c < 4; c++) ts[rg * 4 + r][cg * 4 + c] = acc[r][c];
  __syncthreads();
  int wv = t >> 6, ln = t & 63;
  for (int rr = wv; rr < 64; rr += 4) {
    int gr = r0 + rr;
    if (gr >= rend) break;
    float v = ts[rr][ln];
    float mu = wsum(v) * (1.0f / HIDC);
    float d = v - mu;
    float var = wsum(d * d) * (1.0f / HIDC);
    float yv = g[ln] * d * rsqrtf(var + 1e-5f) + be[ln];
    h[(size_t)gr * HIDC + ln] = fmaxf(yv, 0.0f);
  }
}

#define FUSE_T (64 * 192 + 192)
__global__ __launch_bounds__(256) void k_fuse(
    const float* __restrict__ qw0, const float* __restrict__ qb0,
    const float* __restrict__ kw0, const float* __restrict__ kb0,
    const float* __restrict__ vw0, const float* __restrict__ vb0,
    const float* __restrict__ ar0, const float* __restrict__ mr0,
    const float* __restrict__ p0,
    const float* __restrict__ qw1, const float* __restrict__ qb1,
    const float* __restrict__ kw1, const float* __restrict__ kb1,
    const float* __restrict__ vw1, const float* __restrict__ vb1,
    const float* __restrict__ ar1, const float* __restrict__ mr1,
    const float* __restrict__ p1,
    float* __restrict__ Wf, float* __restrict__ bfv) {
  int gidx = blockIdx.x * 256 + threadIdx.x;
  if (gidx >= 2 * FUSE_T) return;
  int type = gidx >= FUSE_T;
  int idx = gidx - type * FUSE_T;
  const float* qw = type ? qw1 : qw0; const float* qb = type ? qb1 : qb0;
  const float* kw = type ? kw1 : kw0; const float* kb = type ? kb1 : kb0;
  const float* vw = type ? vw1 : vw0; const float* vb = type ? vb1 : vb0;
  const float* ar = type ? ar1 : ar0; const float* mr = type ? mr1 : mr0;
  const float* p  = type ? p1  : p0;
  float* W = Wf + (size_t)type * 64 * 192;
  float* B = bfv + (size_t)type * 192;
  if (idx < 64 * 192) {
    int i = idx / 192, c = idx % 192;
    float o;
    if (c < 64) {
      o = qw[i * 64 + c];
    } else {
      int e = c & 63, hd = e >> 5, ee = e & 31;
      bool isK = c < 128;
      const float* M = isK ? ar : mr;
      const float* Wsrc = isK ? kw : vw;
      float s = 0.0f;
      #pragma unroll
      for (int d = 0; d < 32; ++d)
        s += Wsrc[i * 64 + hd * 32 + d] * M[hd * 32 * 32 + d * 32 + ee];
      if (isK) s *= p[hd] * 0.17677669529663687f;
      o = s;
    }
    W[i * 192 + c] = o;
  } else {
    int c = idx - 64 * 192;
    float o;
    if (c < 64) {
      o = qb[c];
    } else {
      int e = c & 63, hd = e >> 5, ee = e & 31;
      bool isK = c < 128;
      const float* M = isK ? ar : mr;
      const float* Bb = isK ? kb : vb;
      float s = 0.0f;
      #pragma unroll
      for (int d = 0; d < 32; ++d)
        s += Bb[hd * 32 + d] * M[hd * 32 * 32 + d * 32 + ee];
      if (isK) s *= p[hd] * 0.17677669529663687f;
      o = s;
    }
    B[c] = o;
  }
}

__global__ __launch_bounds__(256) void k_kqv2(
    const float* __restrict__ h, const float* __restrict__ Wf,
    const float* __restrict__ bfv,
    u16* __restrict__ qo, u32* __restrict__ kvt) {
  __shared__ float ws_[64 * 192];
  __shared__ float hs[64][65];
  int t = threadIdx.x;
  int b = blockIdx.x;
  int type = b >= KQV_BLKS;
  int r0   = type ? (NN + (b - KQV_BLKS) * 64) : (b * 64);
  int rend = type ? NN2 : NN;
  const float* W = Wf + (size_t)type * 64 * 192;
  const float* B = bfv + (size_t)type * 192;
  for (int i = t; i < 64 * 192 / 4; i += 256)
    ((float4*)ws_)[i] = ((const float4*)W)[i];
  for (int i = t; i < 64 * 16; i += 256) {
    int row = i >> 4, c4 = i & 15;
    int gr = r0 + row; if (gr >= rend) gr = rend - 1;
    float4 v = *(const float4*)&h[(size_t)gr * 64 + c4 * 4];
    hs[row][c4 * 4 + 0] = v.x; hs[row][c4 * 4 + 1] = v.y;
    hs[row][c4 * 4 + 2] = v.z; hs[row][c4 * 4 + 3] = v.w;
  }
  __syncthreads();
  int rg = t & 15, cg = t >> 4;
  float acc[3][4][4];
  #pragma unroll
  for (int j = 0; j < 3; j++) {
    #pragma unroll
    for (int c = 0; c < 4; c++) {
      float bv = B[j * 64 + cg * 4 + c];
      #pragma unroll
      for (int r = 0; r < 4; r++) acc[j][r][c] = bv;
    }
  }
  for (int k = 0; k < 64; ++k) {
    float a0 = hs[rg * 4 + 0][k];
    float a1 = hs[rg * 4 + 1][k];
    float a2 = hs[rg * 4 + 2][k];
    float a3 = hs[rg * 4 + 3][k];
    #pragma unroll
    for (int j = 0; j < 3; j++) {
      float4 w = *(const float4*)&ws_[k * 192 + j * 64 + cg * 4];
      acc[j][0][0] = fmaf(a0, w.x, acc[j][0][0]);
      acc[j][0][1] = fmaf(a0, w.y, acc[j][0][1]);
      acc[j][0][2] = fmaf(a0, w.z, acc[j][0][2]);
      acc[j][0][3] = fmaf(a0, w.w, acc[j][0][3]);
      acc[j][1][0] = fmaf(a1, w.x, acc[j][1][0]);
      acc[j][1][1] = fmaf(a1, w.y, acc[j][1][1]);
      acc[j][1][2] = fmaf(a1, w.z, acc[j][1][2]);
      acc[j][1][3] = fmaf(a1, w.w, acc[j][1][3]);
      acc[j][2][0] = fmaf(a2, w.x, acc[j][2][0]);
      acc[j][2][1] = fmaf(a2, w.y, acc[j][2][1]);
      acc[j][2][2] = fmaf(a2, w.z, acc[j][2][2]);
      acc[j][2][3] = fmaf(a2, w.w, acc[j][2][3]);
      acc[j][3][0] = fmaf(a3, w.x, acc[j][3][0]);
      acc[j][3][1] = fmaf(a3, w.y, acc[j][3][1]);
      acc[j][3][2] = fmaf(a3, w.z, acc[j][3][2]);
      acc[j][3][3] = fmaf(a3, w.w, acc[j][3][3]);
    }
  }
  #pragma unroll
  for (int r = 0; r < 4; ++r) {
    int gr = r0 + rg * 4 + r;
    if (gr >= rend) break;
    u32 q0 = (u32)f2bf(acc[0][r][0]) | ((u32)f2bf(acc[0][r][1]) << 16);
    u32 q1 = (u32)f2bf(acc[0][r][2]) | ((u32)f2bf(acc[0][r][3]) << 16);
    *(u32*)&qo[(size_t)gr * 64 + cg * 4]     = q0;
    *(u32*)&qo[(size_t)gr * 64 + cg * 4 + 2] = q1;
    #pragma unroll
    for (int c = 0; c < 4; ++c) {
      u32 kv = (u32)f2bf(acc[1][r][c]) | ((u32)f2bf(acc[2][r][c]) << 16);
      kvt[(size_t)gr * 64 + cg * 4 + c] = kv;
    }
  }
}

// y = LN(g*(gelu(agg)@Ow+Ob) + (2-g)*h): tile GEMM + LDS LN epilogue
__global__ __launch_bounds__(256) void k_out2(
    const float* __restrict__ agg, const float* __restrict__ h,
    const float* __restrict__ ow0, const float* __restrict__ ob0,
    const float* __restrict__ skip0,
    const float* __restrict__ ow1, const float* __restrict__ ob1,
    const float* __restrict__ skip1,
    const float* __restrict__ lg, const float* __restrict__ lb,
    float* __restrict__ y) {
  __shared__ float ows[64 * 64];           // 16 KB (k-major)
  __shared__ float gs[64][65];             // gelu tile, reused for conv+h
  int t = threadIdx.x;
  int b = blockIdx.x;
  int type = b >= KQV_BLKS;
  int r0   = type ? (NN + (b - KQV_BLKS) * 64) : (b * 64);
  int rend = type ? NN2 : NN;
  const float* ow = type ? ow1 : ow0;
  const float* ob = type ? ob1 : ob0;
  float gk = 1.0f / (1.0f + expf(-(type ? skip1 : skip0)[0]));
  for (int i = t; i < 64 * 64 / 4; i += 256)
    ((float4*)ows)[i] = ((const float4*)ow)[i];
  for (int i = t; i < 64 * 16; i += 256) {
    int row = i >> 4, c4 = i & 15;
    int gr = r0 + row; if (gr >= rend) gr = rend - 1;
    float4 v = *(const float4*)&agg[(size_t)gr * 64 + c4 * 4];
    gs[row][c4 * 4 + 0] = 0.5f * v.x * (1.0f + erff(v.x * 0.70710678118654752f));
    gs[row][c4 * 4 + 1] = 0.5f * v.y * (1.0f + erff(v.y * 0.70710678118654752f));
    gs[row][c4 * 4 + 2] = 0.5f * v.z * (1.0f + erff(v.z * 0.70710678118654752f));
    gs[row][c4 * 4 + 3] = 0.5f * v.w * (1.0f + erff(v.w * 0.70710678118654752f));
  }
  __syncthreads();
  int rg = t & 15, cg = t >> 4;
  float acc[4][4];
  #pragma unroll
  for (int c = 0; c < 4; c++) {
    float bv = ob[cg * 4 + c];
    #pragma unroll
    for (int r = 0; r < 4; r++) acc[r][c] = bv;
  }
  for (int k = 0; k < 64; ++k) {
    float a0 = gs[rg * 4 + 0][k];
    float a1 = gs[rg * 4 + 1][k];
    float a2 = gs[rg * 4 + 2][k];
    float a3 = gs[rg * 4 + 3][k];
    float4 wv4 = *(const float4*)&ows[k * 64 + cg * 4];
    acc[0][0] = fmaf(a0, wv4.x, acc[0][0]); acc[0][1] = fmaf(a0, wv4.y, acc[0][1]);
    acc[0][2] = fmaf(a0, wv4.z, acc[0][2]); acc[0][3] = fmaf(a0, wv4.w, acc[0][3]);
    acc[1][0] = fmaf(a1, wv4.x, acc[1][0]); acc[1][1] = fmaf(a1, wv4.y, acc[1][1]);
    acc[1][2] = fmaf(a1, wv4.z, acc[1][2]); acc[1][3] = fmaf(a1, wv4.w, acc[1][3]);
    acc[2][0] = fmaf(a2, wv4.x, acc[2][0]); acc[2][1] = fmaf(a2, wv4.y, acc[2][1]);
    acc[2][2] = fmaf(a2, wv4.z, acc[2][2]); acc[2][3] = fmaf(a2, wv4.w, acc[2][3]);
    acc[3][0] = fmaf(a3, wv4.x, acc[3][0]); acc[3][1] = fmaf(a3, wv4.y, acc[3][1]);
    acc[3][2] = fmaf(a3, wv4.z, acc[3][2]); acc[3][3] = fmaf(a3, wv4.w, acc[3][3]);
  }
  // conv + h = gk*a + (2-gk)*h
  float tv[4][4];
  float c2 = 2.0f - gk;
  #pragma unroll
  for (int r = 0; r < 4; r++) {
    int gr = r0 + rg * 4 + r; if (gr >= rend) gr = rend - 1;
    float4 hv = *(const float4*)&h[(size_t)gr * 64 + cg * 4];
    tv[r][0] = fmaf(gk, acc[r][0], c2 * hv.x);
    tv[r][1] = fmaf(gk, acc[r][1], c2 * hv.y);
    tv[r][2] = fmaf(gk, acc[r][2], c2 * hv.z);
    tv[r][3] = fmaf(gk, acc[r][3], c2 * hv.w);
  }
  __syncthreads();
  #pragma unroll
  for (int r = 0; r < 4; r++)
    #pragma unroll
    for (int c = 0; c < 4; c++) gs[rg * 4 + r][cg * 4 + c] = tv[r][c];
  __syncthreads();
  int wv = t >> 6, ln = t & 63;
  for (int rr = wv; rr < 64; rr += 4) {
    int gr = r0 + rr;
    if (gr >= rend) break;
    float v = gs[rr][ln];
    float mu = wsum(v) * (1.0f / HIDC);
    float d = v - mu;
    float var = wsum(d * d) * (1.0f / HIDC);
    y[(size_t)gr * HIDC + ln] = lg[ln] * d * rsqrtf(var + 1e-5f) + lb[ln];
  }
}

// ---------- bucketed edge pipeline ----------

__global__ __launch_bounds__(256) void k_gzero(u32* __restrict__ gh) {
  int i = blockIdx.x * 256 + threadIdx.x;
  if (i < NBP) gh[i] = 0;
}

__global__ __launch_bounds__(256) void k_bhist(
    const int* __restrict__ ei_m2b, const int* __restrict__ ei_b2m,
    u32* __restrict__ gh) {
  __shared__ u32 hist[NBP];
  int tid = threadIdx.x;
  for (int i = tid; i < NBP; i += 256) hist[i] = 0;
  __syncthreads();
  int base_e = blockIdx.x * EPB;
  #pragma unroll
  for (int i = 0; i < EPB / 256; i++) {
    int ee = base_e + i * 256 + tid;
    if (ee < 2 * NE) {
      int src_g, dst_g;
      edge_decode(ee, ei_m2b, ei_b2m, src_g, dst_g);
      atomicAdd(&hist[dst_g >> 8], 1u);
    }
  }
  __syncthreads();
  for (int b = tid; b < NBP; b += 256) {
    u32 c = hist[b];
    if (c) atomicAdd(&gh[b], c);
  }
}

__global__ __launch_bounds__(256) void k_bscan(
    const u32* __restrict__ gh, u32* __restrict__ bstart, u32* __restrict__ gcursor) {
  __shared__ u32 a[NBP];
  __shared__ u32 wtot[4];
  int t = threadIdx.x;
  for (int i = t; i < NBP; i += 256) a[i] = (i < NB) ? gh[i] : 0u;
  __syncthreads();
  scan1024(a, wtot);
  __syncthreads();
  for (int i = t; i < NB; i += 256) { bstart[i] = a[i]; gcursor[i] = a[i]; }
  if (t == 0) bstart[NB] = 2 * NE;
}

__global__ __launch_bounds__(256) void k_bscatter(
    const int* __restrict__ ei_m2b, const int* __restrict__ ei_b2m,
    u32* __restrict__ gcursor, u32* __restrict__ bpairs) {
  __shared__ u32 hist[NBP];
  __shared__ u32 loff[NBP];
  __shared__ u32 gbase[NBP];
  __shared__ u32 wtot[4];
  __shared__ u32 pairs[EPB];
  __shared__ u16 sbuck[EPB];
  int tid = threadIdx.x;
  for (int i = tid; i < NBP; i += 256) hist[i] = 0;
  __syncthreads();
  int base_e = blockIdx.x * EPB;
  u32 pk[EPB / 256];
  u16 bk[EPB / 256];
  u16 rk[EPB / 256];
  #pragma unroll
  for (int i = 0; i < EPB / 256; i++) {
    int ee = base_e + i * 256 + tid;
    if (ee < 2 * NE) {
      int src_g, dst_g;
      edge_decode(ee, ei_m2b, ei_b2m, src_g, dst_g);
      u32 b = (u32)dst_g >> 8;
      pk[i] = ((u32)(dst_g & 255) << 18) | (u32)src_g;
      bk[i] = (u16)b;
      rk[i] = (u16)atomicAdd(&hist[b], 1u);
    } else {
      bk[i] = 0xFFFFu;
    }
  }
  __syncthreads();
  for (int i = tid; i < NBP; i += 256) loff[i] = hist[i];
  __syncthreads();
  scan1024(loff, wtot);
  __syncthreads();
  #pragma unroll
  for (int i = 0; i < EPB / 256; i++) {
    if (bk[i] != 0xFFFFu) {
      u32 s = loff[bk[i]] + rk[i];
      pairs[s] = pk[i];
      sbuck[s] = bk[i];
    }
  }
  __syncthreads();
  for (int b = tid; b < NBP; b += 256) {
    u32 c = hist[b];
    gbase[b] = c ? atomicAdd(&gcursor[b], c) : 0u;
  }
  __syncthreads();
  int nval = 2 * NE - base_e;
  if (nval > EPB) nval = EPB;
  for (int s = tid; s < nval; s += 256) {
    u32 b = sbuck[s];
    bpairs[gbase[b] + (s - loff[b])] = pairs[s];
  }
}

__global__ __launch_bounds__(512) void k_bedge(
    const u32* __restrict__ bstart, const u32* __restrict__ bpairs,
    const u16* __restrict__ q, const u32* __restrict__ kvt,
    float* __restrict__ agg) {
  __shared__ u32 pairs[CAP];
  __shared__ u32 srt[CAP];
  __shared__ u32 hist[256];
  __shared__ u32 rowptr[257];
  int tid = threadIdx.x;
  int b = blockIdx.x;
  u32 r0 = bstart[b], r1 = bstart[b + 1];
  int n = (int)(r1 - r0);
  if (n > CAP) n = CAP;
  for (int i = tid; i < 256; i += 512) hist[i] = 0;
  __syncthreads();
  for (int i = tid; i < n; i += 512) {
    u32 p = bpairs[r0 + i];
    pairs[i] = p;
    atomicAdd(&hist[p >> 18], 1u);
  }
  __syncthreads();
  if (tid < 64) {
    int lane = tid;
    u32 v0 = hist[tid * 4 + 0], v1 = hist[tid * 4 + 1];
    u32 v2 = hist[tid * 4 + 2], v3 = hist[tid * 4 + 3];
    u32 sum = v0 + v1 + v2 + v3;
    u32 x = sum;
    #pragma unroll
    for (int off = 1; off < 64; off <<= 1) {
      u32 y = __shfl_up(x, off, 64);
      if (lane >= off) x += y;
    }
    u32 base = x - sum;
    rowptr[tid * 4 + 0] = base;
    rowptr[tid * 4 + 1] = base + v0;
    rowptr[tid * 4 + 2] = base + v0 + v1;
    rowptr[tid * 4 + 3] = base + v0 + v1 + v2;
    if (tid == 63) rowptr[256] = x;
  }
  __syncthreads();
  for (int i = tid; i < 256; i += 512) hist[i] = rowptr[i];
  __syncthreads();
  for (int i = tid; i < n; i += 512) {
    u32 p = pairs[i];
    u32 pos = atomicAdd(&hist[p >> 18], 1u);
    srt[pos] = p & 0x3FFFFu;
  }
  __syncthreads();
  int wv = tid >> 6, ln = tid & 63, g = ln >> 4, t = ln & 15;
  for (int d8 = wv; d8 < 256; d8 += 8) {
    int dst_g = (b << 8) + d8;
    if (dst_g >= NN2) break;
    u32 j0 = rowptr[d8], j1 = rowptr[d8 + 1];
    uint2 qp = *(const uint2*)&q[(size_t)dst_g * 64 + t * 4];
    float q0 = bf2f(qp.x & 0xFFFFu), q1 = bf2f(qp.x >> 16);
    float q2 = bf2f(qp.y & 0xFFFFu), q3 = bf2f(qp.y >> 16);
    float m = -1e30f, s = 0.0f;
    float a0 = 0.0f, a1 = 0.0f, a2 = 0.0f, a3 = 0.0f;
    for (u32 j = j0 + g; j < j1; j += 4) {
      u32 src = srt[j];
      uint4 w = *(const uint4*)&kvt[(size_t)src * 64 + t * 4];
      float k0 = bf2f(w.x & 0xFFFFu), v0 = bf2f(w.x >> 16);
      float k1 = bf2f(w.y & 0xFFFFu), v1 = bf2f(w.y >> 16);
      float k2 = bf2f(w.z & 0xFFFFu), v2 = bf2f(w.z >> 16);
      float k3 = bf2f(w.w & 0xFFFFu), v3 = bf2f(w.w >> 16);
      float prod = fmaf(q3, k3, fmaf(q2, k2, fmaf(q1, k1, q0 * k0)));
      prod += __shfl_xor(prod, 1, 64);
      prod += __shfl_xor(prod, 2, 64);
      prod += __shfl_xor(prod, 4, 64);
      float mn = fmaxf(m, prod);
      float c = __expf(m - mn);
      float we = __expf(prod - mn);
      s = fmaf(s, c, we);
      a0 = fmaf(a0, c, we * v0);
      a1 = fmaf(a1, c, we * v1);
      a2 = fmaf(a2, c, we * v2);
      a3 = fmaf(a3, c, we * v3);
      m = mn;
    }
    #pragma unroll
    for (int off = 16; off <= 32; off <<= 1) {
      float om = __shfl_xor(m, off, 64);
      float os = __shfl_xor(s, off, 64);
      float o0 = __shfl_xor(a0, off, 64);
      float o1 = __shfl_xor(a1, off, 64);
      float o2 = __shfl_xor(a2, off, 64);
      float o3 = __shfl_xor(a3, off, 64);
      float mn = fmaxf(m, om);
      float c1 = __expf(m - mn), c2 = __expf(om - mn);
      s = s * c1 + os * c2;
      a0 = a0 * c1 + o0 * c2;
      a1 = a1 * c1 + o1 * c2;
      a2 = a2 * c1 + o2 * c2;
      a3 = a3 * c1 + o3 * c2;
      m = mn;
    }
    if (g == 0) {
      float inv = 1.0f / (s + 1e-16f);
      float4 o = { a0 * inv, a1 * inv, a2 * inv, a3 * inv };
      *(float4*)&agg[(size_t)dst_g * 64 + t * 4] = o;
    }
  }
}

// ---------- launch ----------
extern "C" void kernel_launch(void* const* d_in, const int* in_sizes, int n_in,
                              void* d_out, int out_size, void* d_ws, size_t ws_size,
                              hipStream_t stream) {
  const float* x_mac     = (const float*)d_in[0];
  const float* x_buf     = (const float*)d_in[1];
  const int*   ei_m2b    = (const int*)d_in[2];
  const int*   ei_b2m    = (const int*)d_in[3];
  const float* enc_w_mac = (const float*)d_in[4];
  const float* enc_b_mac = (const float*)d_in[5];
  const float* enc_g_mac = (const float*)d_in[6];
  const float* enc_be_mac= (const float*)d_in[7];
  const float* k_w_mac   = (const float*)d_in[8];
  const float* k_b_mac   = (const float*)d_in[9];
  const float* q_w_mac   = (const float*)d_in[10];
  const float* q_b_mac   = (const float*)d_in[11];
  const float* v_w_mac   = (const float*)d_in[12];
  const float* v_b_mac   = (const float*)d_in[13];
  const float* o_w_mac   = (const float*)d_in[14];
  const float* o_b_mac   = (const float*)d_in[15];
  const float* skip_mac  = (const float*)d_in[16];
  const float* enc_w_buf = (const float*)d_in[17];
  const float* enc_b_buf = (const float*)d_in[18];
  const float* enc_g_buf = (const float*)d_in[19];
  const float* enc_be_buf= (const float*)d_in[20];
  const float* k_w_buf   = (const float*)d_in[21];
  const float* k_b_buf   = (const float*)d_in[22];
  const float* q_w_buf   = (const float*)d_in[23];
  const float* q_b_buf   = (const float*)d_in[24];
  const float* v_w_buf   = (const float*)d_in[25];
  const float* v_b_buf   = (const float*)d_in[26];
  const float* o_w_buf   = (const float*)d_in[27];
  const float* o_b_buf   = (const float*)d_in[28];
  const float* skip_buf  = (const float*)d_in[29];
  const float* a_m2b     = (const float*)d_in[30];
  const float* m_m2b     = (const float*)d_in[31];
  const float* p_m2b     = (const float*)d_in[32];
  const float* a_b2m     = (const float*)d_in[33];
  const float* m_b2m     = (const float*)d_in[34];
  const float* p_b2m     = (const float*)d_in[35];
  const float* ln_g      = (const float*)d_in[36];
  const float* ln_b      = (const float*)d_in[37];

  char* ws = (char*)d_ws;
  size_t off = 0;
  auto take = [&](size_t bytes) -> char* {
    char* p = ws + off;
    off = (off + bytes + 255) & ~(size_t)255;
    return p;
  };
  float* h       = (float*)take((size_t)NN2 * HIDC * 4);
  float* agg     = (float*)take((size_t)NN2 * HIDC * 4);
  u16*   q       = (u16*)take((size_t)NN2 * HIDC * 2);
  u32*   kvt     = (u32*)take((size_t)NN2 * HIDC * 4);
  float* Wf      = (float*)take((size_t)2 * 64 * 192 * 4);
  float* bfv     = (float*)take((size_t)2 * 192 * 4);
  u32*   ghist   = (u32*)take((size_t)NBP * 4);
  u32*   bstart  = (u32*)take((size_t)(NB + 1) * 4);
  u32*   gcursor = (u32*)take((size_t)NBP * 4);
  u32*   bpairs  = (u32*)take((size_t)2 * NE * 4);

  const int tile_grid = 2 * KQV_BLKS;               // 3126
  const int fuse_grid = (2 * FUSE_T + 255) / 256;   // 98

  k_fuse<<<fuse_grid, 256, 0, stream>>>(
      q_w_mac, q_b_mac, k_w_mac, k_b_mac, v_w_mac, v_b_mac, a_m2b, m_m2b, p_m2b,
      q_w_buf, q_b_buf, k_w_buf, k_b_buf, v_w_buf, v_b_buf, a_b2m, m_b2m, p_b2m,
      Wf, bfv);
  k_gzero<<<(NBP + 255) / 256, 256, 0, stream>>>(ghist);
  k_bhist<<<SCGRID, 256, 0, stream>>>(ei_m2b, ei_b2m, ghist);
  k_enc2<<<tile_grid, 256, 0, stream>>>(
      x_mac, x_buf,
      enc_w_mac, enc_b_mac, enc_g_mac, enc_be_mac,
      enc_w_buf, enc_b_buf, enc_g_buf, enc_be_buf, h);
  k_bscan<<<1, 256, 0, stream>>>(ghist, bstart, gcursor);
  k_bscatter<<<SCGRID, 256, 0, stream>>>(ei_m2b, ei_b2m, gcursor, bpairs);
  k_kqv2<<<tile_grid, 256, 0, stream>>>(h, Wf, bfv, q, kvt);
  k_bedge<<<NB, 512, 0, stream>>>(bstart, bpairs, q, kvt, agg);
  k_out2<<<tile_grid, 256, 0, stream>>>(
      agg, h, o_w_mac, o_b_mac, skip_mac, o_w_buf, o_b_buf, skip_buf,
      ln_g, ln_b, (float*)d_out);
}

// Round 7
// 342.031 us; speedup vs baseline: 23.5605x; 1.0389x over previous
//
#include <hip/hip_runtime.h>
#include <hip/hip_bf16.h>
#include <math.h>

#define NN 100000
#define NN2 200000
#define NE 1000000
#define FIN 32
#define HIDC 64

#define NB 782            // ceil(NN2/256) buckets of 256 dsts
#define NBP 1024          // padded
#define EPB 4096          // edges per scatter/hist block
#define SCGRID 489        // ceil(2*NE / EPB)
#define CAP 3072          // max edges per bucket (mean 2560, +10 sigma)
#define CAPH 1536         // max edges per half-bucket (mean 1280)
#define MAXIT 12          // CAP / 256
#define KQV_BLKS 1563     // ceil(NN/64)

typedef unsigned int u32;
typedef unsigned short u16;

// ---------- helpers ----------
__device__ __forceinline__ float wsum(float v) {
  #pragma unroll
  for (int off = 32; off; off >>= 1) v += __shfl_xor(v, off, 64);
  return v;
}

__device__ __forceinline__ u16 f2bf(float f) {
  union { float f; u32 u; } c; c.f = f;
  u32 u = c.u;
  return (u16)((u + 0x7FFFu + ((u >> 16) & 1u)) >> 16);
}

__device__ __forceinline__ float bf2f(u32 v) {  // low 16 bits = bf16
  union { u32 u; float f; } c; c.u = v << 16; return c.f;
}

// in-place exclusive scan of a[1024] by 256 threads (4 entries/thread)
__device__ __forceinline__ void scan1024(u32* a, u32* wtot) {
  int t = threadIdx.x, lane = t & 63, wv = t >> 6;
  u32 v0 = a[t * 4 + 0], v1 = a[t * 4 + 1], v2 = a[t * 4 + 2], v3 = a[t * 4 + 3];
  u32 sum = v0 + v1 + v2 + v3;
  u32 x = sum;
  #pragma unroll
  for (int off = 1; off < 64; off <<= 1) {
    u32 y = __shfl_up(x, off, 64);
    if (lane >= off) x += y;
  }
  if (lane == 63) wtot[wv] = x;
  u32 excl = x - sum;
  __syncthreads();
  u32 wb = 0;
  #pragma unroll
  for (int w = 0; w < 4; w++) if (w < wv) wb += wtot[w];
  u32 b = wb + excl;
  a[t * 4 + 0] = b;
  a[t * 4 + 1] = b + v0;
  a[t * 4 + 2] = b + v0 + v1;
  a[t * 4 + 3] = b + v0 + v1 + v2;
}

__device__ __forceinline__ void edge_decode(
    int ee, const int* __restrict__ ei_m2b, const int* __restrict__ ei_b2m,
    int& src_g, int& dst_g) {
  if (ee < NE) {
    src_g = ei_m2b[ee];
    dst_g = NN + ei_m2b[NE + ee];
  } else {
    int e2 = ee - NE;
    src_g = NN + ei_b2m[e2];
    dst_g = ei_b2m[NE + e2];
  }
}

// ---------- node kernels (64-row tile GEMMs; mac tiles 0..1562, buf 1563..3125) ----------

__global__ __launch_bounds__(256) void k_enc2(
    const float* __restrict__ x_mac, const float* __restrict__ x_buf,
    const float* __restrict__ w_mac, const float* __restrict__ b_mac,
    const float* __restrict__ g_mac, const float* __restrict__ be_mac,
    const float* __restrict__ w_buf, const float* __restrict__ b_buf,
    const float* __restrict__ g_buf, const float* __restrict__ be_buf,
    float* __restrict__ h) {
  __shared__ float ws_[FIN * HIDC];
  __shared__ float xs[64][FIN + 1];
  __shared__ float ts[64][HIDC + 1];
  int t = threadIdx.x;
  int b = blockIdx.x;
  int type = b >= KQV_BLKS;
  int r0   = type ? (NN + (b - KQV_BLKS) * 64) : (b * 64);
  int rend = type ? NN2 : NN;
  const float* w  = type ? w_buf  : w_mac;
  const float* bb = type ? b_buf  : b_mac;
  const float* g  = type ? g_buf  : g_mac;
  const float* be = type ? be_buf : be_mac;
  const float* x  = type ? x_buf  : x_mac;
  int xoff = type ? NN : 0;
  for (int i = t; i < FIN * HIDC / 4; i += 256)
    ((float4*)ws_)[i] = ((const float4*)w)[i];
  for (int i = t; i < 64 * 8; i += 256) {
    int row = i >> 3, c4 = i & 7;
    int gr = r0 + row; if (gr >= rend) gr = rend - 1;
    float4 v = *(const float4*)&x[(size_t)(gr - xoff) * FIN + c4 * 4];
    xs[row][c4 * 4 + 0] = v.x; xs[row][c4 * 4 + 1] = v.y;
    xs[row][c4 * 4 + 2] = v.z; xs[row][c4 * 4 + 3] = v.w;
  }
  __syncthreads();
  int rg = t & 15, cg = t >> 4;
  float acc[4][4];
  #pragma unroll
  for (int c = 0; c < 4; c++) {
    float bv = bb[cg * 4 + c];
    #pragma unroll
    for (int r = 0; r < 4; r++) acc[r][c] = bv;
  }
  for (int k = 0; k < FIN; ++k) {
    float a0 = xs[rg * 4 + 0][k];
    float a1 = xs[rg * 4 + 1][k];
    float a2 = xs[rg * 4 + 2][k];
    float a3 = xs[rg * 4 + 3][k];
    float4 wv4 = *(const float4*)&ws_[k * HIDC + cg * 4];
    acc[0][0] = fmaf(a0, wv4.x, acc[0][0]); acc[0][1] = fmaf(a0, wv4.y, acc[0][1]);
    acc[0][2] = fmaf(a0, wv4.z, acc[0][2]); acc[0][3] = fmaf(a0, wv4.w, acc[0][3]);
    acc[1][0] = fmaf(a1, wv4.x, acc[1][0]); acc[1][1] = fmaf(a1, wv4.y, acc[1][1]);
    acc[1][2] = fmaf(a1, wv4.z, acc[1][2]); acc[1][3] = fmaf(a1, wv4.w, acc[1][3]);
    acc[2][0] = fmaf(a2, wv4.x, acc[2][0]); acc[2][1] = fmaf(a2, wv4.y, acc[2][1]);
    acc[2][2] = fmaf(a2, wv4.z, acc[2][2]); acc[2][3] = fmaf(a2, wv4.w, acc[2][3]);
    acc[3][0] = fmaf(a3, wv4.x, acc[3][0]); acc[3][1] = fmaf(a3, wv4.y, acc[3][1]);
    acc[3][2] = fmaf(a3, wv4.z, acc[3][2]); acc[3][3] = fmaf(a3, wv4.w, acc[3][3]);
  }
  #pragma unroll
  for (int r = 0; r < 4; r++)
    #pragma unroll
    for (int c = 0; c < 4; c++) ts[rg * 4 + r][cg * 4 + c] = acc[r][c];
  __syncthreads();
  int wv = t >> 6, ln = t & 63;
  for (int rr = wv; rr < 64; rr += 4) {
    int gr = r0 + rr;
    if (gr >= rend) break;
    float v = ts[rr][ln];
    float mu = wsum(v) * (1.0f / HIDC);
    float d = v - mu;
    float var = wsum(d * d) * (1.0f / HIDC);
    float yv = g[ln] * d * rsqrtf(var + 1e-5f) + be[ln];
    h[(size_t)gr * HIDC + ln] = fmaxf(yv, 0.0f);
  }
}

#define FUSE_T (64 * 192 + 192)
__global__ __launch_bounds__(256) void k_fuse(
    const float* __restrict__ qw0, const float* __restrict__ qb0,
    const float* __restrict__ kw0, const float* __restrict__ kb0,
    const float* __restrict__ vw0, const float* __restrict__ vb0,
    const float* __restrict__ ar0, const float* __restrict__ mr0,
    const float* __restrict__ p0,
    const float* __restrict__ qw1, const float* __restrict__ qb1,
    const float* __restrict__ kw1, const float* __restrict__ kb1,
    const float* __restrict__ vw1, const float* __restrict__ vb1,
    const float* __restrict__ ar1, const float* __restrict__ mr1,
    const float* __restrict__ p1,
    float* __restrict__ Wf, float* __restrict__ bfv) {
  int gidx = blockIdx.x * 256 + threadIdx.x;
  if (gidx >= 2 * FUSE_T) return;
  int type = gidx >= FUSE_T;
  int idx = gidx - type * FUSE_T;
  const float* qw = type ? qw1 : qw0; const float* qb = type ? qb1 : qb0;
  const float* kw = type ? kw1 : kw0; const float* kb = type ? kb1 : kb0;
  const float* vw = type ? vw1 : vw0; const float* vb = type ? vb1 : vb0;
  const float* ar = type ? ar1 : ar0; const float* mr = type ? mr1 : mr0;
  const float* p  = type ? p1  : p0;
  float* W = Wf + (size_t)type * 64 * 192;
  float* B = bfv + (size_t)type * 192;
  if (idx < 64 * 192) {
    int i = idx / 192, c = idx % 192;
    float o;
    if (c < 64) {
      o = qw[i * 64 + c];
    } else {
      int e = c & 63, hd = e >> 5, ee = e & 31;
      bool isK = c < 128;
      const float* M = isK ? ar : mr;
      const float* Wsrc = isK ? kw : vw;
      float s = 0.0f;
      #pragma unroll
      for (int d = 0; d < 32; ++d)
        s += Wsrc[i * 64 + hd * 32 + d] * M[hd * 32 * 32 + d * 32 + ee];
      if (isK) s *= p[hd] * 0.17677669529663687f;
      o = s;
    }
    W[i * 192 + c] = o;
  } else {
    int c = idx - 64 * 192;
    float o;
    if (c < 64) {
      o = qb[c];
    } else {
      int e = c & 63, hd = e >> 5, ee = e & 31;
      bool isK = c < 128;
      const float* M = isK ? ar : mr;
      const float* Bb = isK ? kb : vb;
      float s = 0.0f;
      #pragma unroll
      for (int d = 0; d < 32; ++d)
        s += Bb[hd * 32 + d] * M[hd * 32 * 32 + d * 32 + ee];
      if (isK) s *= p[hd] * 0.17677669529663687f;
      o = s;
    }
    B[c] = o;
  }
}

__global__ __launch_bounds__(256) void k_kqv2(
    const float* __restrict__ h, const float* __restrict__ Wf,
    const float* __restrict__ bfv,
    u16* __restrict__ qo, u32* __restrict__ kvt) {
  __shared__ float ws_[64 * 192];
  __shared__ float hs[64][65];
  int t = threadIdx.x;
  int b = blockIdx.x;
  int type = b >= KQV_BLKS;
  int r0   = type ? (NN + (b - KQV_BLKS) * 64) : (b * 64);
  int rend = type ? NN2 : NN;
  const float* W = Wf + (size_t)type * 64 * 192;
  const float* B = bfv + (size_t)type * 192;
  for (int i = t; i < 64 * 192 / 4; i += 256)
    ((float4*)ws_)[i] = ((const float4*)W)[i];
  for (int i = t; i < 64 * 16; i += 256) {
    int row = i >> 4, c4 = i & 15;
    int gr = r0 + row; if (gr >= rend) gr = rend - 1;
    float4 v = *(const float4*)&h[(size_t)gr * 64 + c4 * 4];
    hs[row][c4 * 4 + 0] = v.x; hs[row][c4 * 4 + 1] = v.y;
    hs[row][c4 * 4 + 2] = v.z; hs[row][c4 * 4 + 3] = v.w;
  }
  __syncthreads();
  int rg = t & 15, cg = t >> 4;
  float acc[3][4][4];
  #pragma unroll
  for (int j = 0; j < 3; j++) {
    #pragma unroll
    for (int c = 0; c < 4; c++) {
      float bv = B[j * 64 + cg * 4 + c];
      #pragma unroll
      for (int r = 0; r < 4; r++) acc[j][r][c] = bv;
    }
  }
  for (int k = 0; k < 64; ++k) {
    float a0 = hs[rg * 4 + 0][k];
    float a1 = hs[rg * 4 + 1][k];
    float a2 = hs[rg * 4 + 2][k];
    float a3 = hs[rg * 4 + 3][k];
    #pragma unroll
    for (int j = 0; j < 3; j++) {
      float4 w = *(const float4*)&ws_[k * 192 + j * 64 + cg * 4];
      acc[j][0][0] = fmaf(a0, w.x, acc[j][0][0]);
      acc[j][0][1] = fmaf(a0, w.y, acc[j][0][1]);
      acc[j][0][2] = fmaf(a0, w.z, acc[j][0][2]);
      acc[j][0][3] = fmaf(a0, w.w, acc[j][0][3]);
      acc[j][1][0] = fmaf(a1, w.x, acc[j][1][0]);
      acc[j][1][1] = fmaf(a1, w.y, acc[j][1][1]);
      acc[j][1][2] = fmaf(a1, w.z, acc[j][1][2]);
      acc[j][1][3] = fmaf(a1, w.w, acc[j][1][3]);
      acc[j][2][0] = fmaf(a2, w.x, acc[j][2][0]);
      acc[j][2][1] = fmaf(a2, w.y, acc[j][2][1]);
      acc[j][2][2] = fmaf(a2, w.z, acc[j][2][2]);
      acc[j][2][3] = fmaf(a2, w.w, acc[j][2][3]);
      acc[j][3][0] = fmaf(a3, w.x, acc[j][3][0]);
      acc[j][3][1] = fmaf(a3, w.y, acc[j][3][1]);
      acc[j][3][2] = fmaf(a3, w.z, acc[j][3][2]);
      acc[j][3][3] = fmaf(a3, w.w, acc[j][3][3]);
    }
  }
  #pragma unroll
  for (int r = 0; r < 4; ++r) {
    int gr = r0 + rg * 4 + r;
    if (gr >= rend) break;
    u32 q0 = (u32)f2bf(acc[0][r][0]) | ((u32)f2bf(acc[0][r][1]) << 16);
    u32 q1 = (u32)f2bf(acc[0][r][2]) | ((u32)f2bf(acc[0][r][3]) << 16);
    *(u32*)&qo[(size_t)gr * 64 + cg * 4]     = q0;
    *(u32*)&qo[(size_t)gr * 64 + cg * 4 + 2] = q1;
    #pragma unroll
    for (int c = 0; c < 4; ++c) {
      u32 kv = (u32)f2bf(acc[1][r][c]) | ((u32)f2bf(acc[2][r][c]) << 16);
      kvt[(size_t)gr * 64 + cg * 4 + c] = kv;
    }
  }
}

__global__ __launch_bounds__(256) void k_out2(
    const float* __restrict__ agg, const float* __restrict__ h,
    const float* __restrict__ ow0, const float* __restrict__ ob0,
    const float* __restrict__ skip0,
    const float* __restrict__ ow1, const float* __restrict__ ob1,
    const float* __restrict__ skip1,
    const float* __restrict__ lg, const float* __restrict__ lb,
    float* __restrict__ y) {
  __shared__ float ows[64 * 64];
  __shared__ float gs[64][65];
  int t = threadIdx.x;
  int b = blockIdx.x;
  int type = b >= KQV_BLKS;
  int r0   = type ? (NN + (b - KQV_BLKS) * 64) : (b * 64);
  int rend = type ? NN2 : NN;
  const float* ow = type ? ow1 : ow0;
  const float* ob = type ? ob1 : ob0;
  float gk = 1.0f / (1.0f + expf(-(type ? skip1 : skip0)[0]));
  for (int i = t; i < 64 * 64 / 4; i += 256)
    ((float4*)ows)[i] = ((const float4*)ow)[i];
  for (int i = t; i < 64 * 16; i += 256) {
    int row = i >> 4, c4 = i & 15;
    int gr = r0 + row; if (gr >= rend) gr = rend - 1;
    float4 v = *(const float4*)&agg[(size_t)gr * 64 + c4 * 4];
    gs[row][c4 * 4 + 0] = 0.5f * v.x * (1.0f + erff(v.x * 0.70710678118654752f));
    gs[row][c4 * 4 + 1] = 0.5f * v.y * (1.0f + erff(v.y * 0.70710678118654752f));
    gs[row][c4 * 4 + 2] = 0.5f * v.z * (1.0f + erff(v.z * 0.70710678118654752f));
    gs[row][c4 * 4 + 3] = 0.5f * v.w * (1.0f + erff(v.w * 0.70710678118654752f));
  }
  __syncthreads();
  int rg = t & 15, cg = t >> 4;
  float acc[4][4];
  #pragma unroll
  for (int c = 0; c < 4; c++) {
    float bv = ob[cg * 4 + c];
    #pragma unroll
    for (int r = 0; r < 4; r++) acc[r][c] = bv;
  }
  for (int k = 0; k < 64; ++k) {
    float a0 = gs[rg * 4 + 0][k];
    float a1 = gs[rg * 4 + 1][k];
    float a2 = gs[rg * 4 + 2][k];
    float a3 = gs[rg * 4 + 3][k];
    float4 wv4 = *(const float4*)&ows[k * 64 + cg * 4];
    acc[0][0] = fmaf(a0, wv4.x, acc[0][0]); acc[0][1] = fmaf(a0, wv4.y, acc[0][1]);
    acc[0][2] = fmaf(a0, wv4.z, acc[0][2]); acc[0][3] = fmaf(a0, wv4.w, acc[0][3]);
    acc[1][0] = fmaf(a1, wv4.x, acc[1][0]); acc[1][1] = fmaf(a1, wv4.y, acc[1][1]);
    acc[1][2] = fmaf(a1, wv4.z, acc[1][2]); acc[1][3] = fmaf(a1, wv4.w, acc[1][3]);
    acc[2][0] = fmaf(a2, wv4.x, acc[2][0]); acc[2][1] = fmaf(a2, wv4.y, acc[2][1]);
    acc[2][2] = fmaf(a2, wv4.z, acc[2][2]); acc[2][3] = fmaf(a2, wv4.w, acc[2][3]);
    acc[3][0] = fmaf(a3, wv4.x, acc[3][0]); acc[3][1] = fmaf(a3, wv4.y, acc[3][1]);
    acc[3][2] = fmaf(a3, wv4.z, acc[3][2]); acc[3][3] = fmaf(a3, wv4.w, acc[3][3]);
  }
  float tv[4][4];
  float c2 = 2.0f - gk;
  #pragma unroll
  for (int r = 0; r < 4; r++) {
    int gr = r0 + rg * 4 + r; if (gr >= rend) gr = rend - 1;
    float4 hv = *(const float4*)&h[(size_t)gr * 64 + cg * 4];
    tv[r][0] = fmaf(gk, acc[r][0], c2 * hv.x);
    tv[r][1] = fmaf(gk, acc[r][1], c2 * hv.y);
    tv[r][2] = fmaf(gk, acc[r][2], c2 * hv.z);
    tv[r][3] = fmaf(gk, acc[r][3], c2 * hv.w);
  }
  __syncthreads();
  #pragma unroll
  for (int r = 0; r < 4; r++)
    #pragma unroll
    for (int c = 0; c < 4; c++) gs[rg * 4 + r][cg * 4 + c] = tv[r][c];
  __syncthreads();
  int wv = t >> 6, ln = t & 63;
  for (int rr = wv; rr < 64; rr += 4) {
    int gr = r0 + rr;
    if (gr >= rend) break;
    float v = gs[rr][ln];
    float mu = wsum(v) * (1.0f / HIDC);
    float d = v - mu;
    float var = wsum(d * d) * (1.0f / HIDC);
    y[(size_t)gr * HIDC + ln] = lg[ln] * d * rsqrtf(var + 1e-5f) + lb[ln];
  }
}

// ---------- bucketed edge pipeline ----------

__global__ __launch_bounds__(256) void k_bhist(
    const int* __restrict__ ei_m2b, const int* __restrict__ ei_b2m,
    u32* __restrict__ gh) {
  __shared__ u32 hist[NBP];
  int tid = threadIdx.x;
  for (int i = tid; i < NBP; i += 256) hist[i] = 0;
  __syncthreads();
  int base_e = blockIdx.x * EPB;
  #pragma unroll
  for (int i = 0; i < EPB / 256; i++) {
    int ee = base_e + i * 256 + tid;
    if (ee < 2 * NE) {
      int src_g, dst_g;
      edge_decode(ee, ei_m2b, ei_b2m, src_g, dst_g);
      atomicAdd(&hist[dst_g >> 8], 1u);
    }
  }
  __syncthreads();
  for (int b = tid; b < NBP; b += 256) {
    u32 c = hist[b];
    if (c) atomicAdd(&gh[b], c);
  }
}

__global__ __launch_bounds__(256) void k_bscan(
    const u32* __restrict__ gh, u32* __restrict__ bstart, u32* __restrict__ gcursor) {
  __shared__ u32 a[NBP];
  __shared__ u32 wtot[4];
  int t = threadIdx.x;
  for (int i = t; i < NBP; i += 256) a[i] = (i < NB) ? gh[i] : 0u;
  __syncthreads();
  scan1024(a, wtot);
  __syncthreads();
  for (int i = t; i < NB; i += 256) { bstart[i] = a[i]; gcursor[i] = a[i]; }
  if (t == 0) bstart[NB] = 2 * NE;
}

__global__ __launch_bounds__(256) void k_bscatter(
    const int* __restrict__ ei_m2b, const int* __restrict__ ei_b2m,
    u32* __restrict__ gcursor, u32* __restrict__ bpairs) {
  __shared__ u32 hist[NBP];
  __shared__ u32 loff[NBP];
  __shared__ u32 gbase[NBP];
  __shared__ u32 wtot[4];
  __shared__ u32 pairs[EPB];
  __shared__ u16 sbuck[EPB];
  int tid = threadIdx.x;
  for (int i = tid; i < NBP; i += 256) hist[i] = 0;
  __syncthreads();
  int base_e = blockIdx.x * EPB;
  u32 pk[EPB / 256];
  u16 bk[EPB / 256];
  u16 rk[EPB / 256];
  #pragma unroll
  for (int i = 0; i < EPB / 256; i++) {
    int ee = base_e + i * 256 + tid;
    if (ee < 2 * NE) {
      int src_g, dst_g;
      edge_decode(ee, ei_m2b, ei_b2m, src_g, dst_g);
      u32 b = (u32)dst_g >> 8;
      pk[i] = ((u32)(dst_g & 255) << 18) | (u32)src_g;
      bk[i] = (u16)b;
      rk[i] = (u16)atomicAdd(&hist[b], 1u);
    } else {
      bk[i] = 0xFFFFu;
    }
  }
  __syncthreads();
  for (int i = tid; i < NBP; i += 256) loff[i] = hist[i];
  __syncthreads();
  scan1024(loff, wtot);
  __syncthreads();
  #pragma unroll
  for (int i = 0; i < EPB / 256; i++) {
    if (bk[i] != 0xFFFFu) {
      u32 s = loff[bk[i]] + rk[i];
      pairs[s] = pk[i];
      sbuck[s] = bk[i];
    }
  }
  __syncthreads();
  for (int b = tid; b < NBP; b += 256) {
    u32 c = hist[b];
    gbase[b] = c ? atomicAdd(&gcursor[b], c) : 0u;
  }
  __syncthreads();
  int nval = 2 * NE - base_e;
  if (nval > EPB) nval = EPB;
  for (int s = tid; s < nval; s += 256) {
    u32 b = sbuck[s];
    bpairs[gbase[b] + (s - loff[b])] = pairs[s];
  }
}

// half-bucket edge kernel: 256 threads = 16 groups of 16 lanes; one group per dst.
// blockIdx = bucket*2 + half; handles 128 dsts.
__global__ __launch_bounds__(256) void k_bedge2(
    const u32* __restrict__ bstart, const u32* __restrict__ bpairs,
    const u16* __restrict__ q, const u32* __restrict__ kvt,
    float* __restrict__ agg) {
  __shared__ u32 srt[CAPH];
  __shared__ u32 hist[128];
  __shared__ u32 rowptr[129];
  int tid = threadIdx.x;
  int b = blockIdx.x >> 1;
  u32 half = blockIdx.x & 1;
  u32 r0 = bstart[b], r1 = bstart[b + 1];
  int n = (int)(r1 - r0);
  if (n > CAP) n = CAP;
  if (tid < 128) hist[tid] = 0;
  __syncthreads();
  // register-stage this block's half of the bucket's pairs
  u32 pk[MAXIT];
  #pragma unroll
  for (int it = 0; it < MAXIT; it++) {
    pk[it] = 0xFFFFFFFFu;
    int i = tid + it * 256;
    if (i < n) {
      u32 p = bpairs[r0 + i];
      u32 ld = p >> 18;                       // 0..255 local dst
      if ((ld >> 7) == half) {
        atomicAdd(&hist[ld & 127], 1u);
        pk[it] = p;
      }
    }
  }
  __syncthreads();
  // scan 128 counts (one wave, 2 elems/lane)
  if (tid < 64) {
    u32 v0 = hist[tid * 2], v1 = hist[tid * 2 + 1];
    u32 sum = v0 + v1;
    u32 x = sum;
    #pragma unroll
    for (int off = 1; off < 64; off <<= 1) {
      u32 y = __shfl_up(x, off, 64);
      if (tid >= off) x += y;
    }
    u32 excl = x - sum;
    rowptr[tid * 2] = excl;
    rowptr[tid * 2 + 1] = excl + v0;
    if (tid == 63) rowptr[128] = x;
  }
  __syncthreads();
  if (tid < 128) hist[tid] = rowptr[tid];    // reuse as cursor
  __syncthreads();
  #pragma unroll
  for (int it = 0; it < MAXIT; it++) {
    u32 p = pk[it];
    if (p != 0xFFFFFFFFu) {
      u32 pos = atomicAdd(&hist[(p >> 18) & 127], 1u);
      srt[pos] = p & 0x3FFFFu;
    }
  }
  __syncthreads();
  // one 16-lane group per dst; 8 dsts per group
  int grp = tid >> 4, t = tid & 15;
  for (int ld = grp; ld < 128; ld += 16) {
    int dst_g = (b << 8) + ((int)half << 7) + ld;
    if (dst_g >= NN2) continue;
    u32 j0 = rowptr[ld], j1 = rowptr[ld + 1];
    uint2 qp = *(const uint2*)&q[(size_t)dst_g * 64 + t * 4];
    float q0 = bf2f(qp.x & 0xFFFFu), q1 = bf2f(qp.x >> 16);
    float q2 = bf2f(qp.y & 0xFFFFu), q3 = bf2f(qp.y >> 16);
    float m = -1e30f, s = 0.0f;
    float a0 = 0.0f, a1 = 0.0f, a2 = 0.0f, a3 = 0.0f;
    u32 j = j0;
    for (; j + 2 <= j1; j += 2) {
      u32 s0 = srt[j], s1 = srt[j + 1];
      uint4 w0 = *(const uint4*)&kvt[(size_t)s0 * 64 + t * 4];
      uint4 w1 = *(const uint4*)&kvt[(size_t)s1 * 64 + t * 4];
      {
        float k0 = bf2f(w0.x & 0xFFFFu), v0 = bf2f(w0.x >> 16);
        float k1 = bf2f(w0.y & 0xFFFFu), v1 = bf2f(w0.y >> 16);
        float k2 = bf2f(w0.z & 0xFFFFu), v2 = bf2f(w0.z >> 16);
        float k3 = bf2f(w0.w & 0xFFFFu), v3 = bf2f(w0.w >> 16);
        float prod = fmaf(q3, k3, fmaf(q2, k2, fmaf(q1, k1, q0 * k0)));
        prod += __shfl_xor(prod, 1, 64);
        prod += __shfl_xor(prod, 2, 64);
        prod += __shfl_xor(prod, 4, 64);
        float mn = fmaxf(m, prod);
        float c = __expf(m - mn);
        float we = __expf(prod - mn);
        s = fmaf(s, c, we);
        a0 = fmaf(a0, c, we * v0);
        a1 = fmaf(a1, c, we * v1);
        a2 = fmaf(a2, c, we * v2);
        a3 = fmaf(a3, c, we * v3);
        m = mn;
      }
      {
        float k0 = bf2f(w1.x & 0xFFFFu), v0 = bf2f(w1.x >> 16);
        float k1 = bf2f(w1.y & 0xFFFFu), v1 = bf2f(w1.y >> 16);
        float k2 = bf2f(w1.z & 0xFFFFu), v2 = bf2f(w1.z >> 16);
        float k3 = bf2f(w1.w & 0xFFFFu), v3 = bf2f(w1.w >> 16);
        float prod = fmaf(q3, k3, fmaf(q2, k2, fmaf(q1, k1, q0 * k0)));
        prod += __shfl_xor(prod, 1, 64);
        prod += __shfl_xor(prod, 2, 64);
        prod += __shfl_xor(prod, 4, 64);
        float mn = fmaxf(m, prod);
        float c = __expf(m - mn);
        float we = __expf(prod - mn);
        s = fmaf(s, c, we);
        a0 = fmaf(a0, c, we * v0);
        a1 = fmaf(a1, c, we * v1);
        a2 = fmaf(a2, c, we * v2);
        a3 = fmaf(a3, c, we * v3);
        m = mn;
      }
    }
    if (j < j1) {
      u32 s0 = srt[j];
      uint4 w0 = *(const uint4*)&kvt[(size_t)s0 * 64 + t * 4];
      float k0 = bf2f(w0.x & 0xFFFFu), v0 = bf2f(w0.x >> 16);
      float k1 = bf2f(w0.y & 0xFFFFu), v1 = bf2f(w0.y >> 16);
      float k2 = bf2f(w0.z & 0xFFFFu), v2 = bf2f(w0.z >> 16);
      float k3 = bf2f(w0.w & 0xFFFFu), v3 = bf2f(w0.w >> 16);
      float prod = fmaf(q3, k3, fmaf(q2, k2, fmaf(q1, k1, q0 * k0)));
      prod += __shfl_xor(prod, 1, 64);
      prod += __shfl_xor(prod, 2, 64);
      prod += __shfl_xor(prod, 4, 64);
      float mn = fmaxf(m, prod);
      float c = __expf(m - mn);
      float we = __expf(prod - mn);
      s = fmaf(s, c, we);
      a0 = fmaf(a0, c, we * v0);
      a1 = fmaf(a1, c, we * v1);
      a2 = fmaf(a2, c, we * v2);
      a3 = fmaf(a3, c, we * v3);
      m = mn;
    }
    float inv = 1.0f / (s + 1e-16f);
    float4 o = { a0 * inv, a1 * inv, a2 * inv, a3 * inv };
    *(float4*)&agg[(size_t)dst_g * 64 + t * 4] = o;
  }
}

// ---------- launch ----------
extern "C" void kernel_launch(void* const* d_in, const int* in_sizes, int n_in,
                              void* d_out, int out_size, void* d_ws, size_t ws_size,
                              hipStream_t stream) {
  const float* x_mac     = (const float*)d_in[0];
  const float* x_buf     = (const float*)d_in[1];
  const int*   ei_m2b    = (const int*)d_in[2];
  const int*   ei_b2m    = (const int*)d_in[3];
  const float* enc_w_mac = (const float*)d_in[4];
  const float* enc_b_mac = (const float*)d_in[5];
  const float* enc_g_mac = (const float*)d_in[6];
  const float* enc_be_mac= (const float*)d_in[7];
  const float* k_w_mac   = (const float*)d_in[8];
  const float* k_b_mac   = (const float*)d_in[9];
  const float* q_w_mac   = (const float*)d_in[10];
  const float* q_b_mac   = (const float*)d_in[11];
  const float* v_w_mac   = (const float*)d_in[12];
  const float* v_b_mac   = (const float*)d_in[13];
  const float* o_w_mac   = (const float*)d_in[14];
  const float* o_b_mac   = (const float*)d_in[15];
  const float* skip_mac  = (const float*)d_in[16];
  const float* enc_w_buf = (const float*)d_in[17];
  const float* enc_b_buf = (const float*)d_in[18];
  const float* enc_g_buf = (const float*)d_in[19];
  const float* enc_be_buf= (const float*)d_in[20];
  const float* k_w_buf   = (const float*)d_in[21];
  const float* k_b_buf   = (const float*)d_in[22];
  const float* q_w_buf   = (const float*)d_in[23];
  const float* q_b_buf   = (const float*)d_in[24];
  const float* v_w_buf   = (const float*)d_in[25];
  const float* v_b_buf   = (const float*)d_in[26];
  const float* o_w_buf   = (const float*)d_in[27];
  const float* o_b_buf   = (const float*)d_in[28];
  const float* skip_buf  = (const float*)d_in[29];
  const float* a_m2b     = (const float*)d_in[30];
  const float* m_m2b     = (const float*)d_in[31];
  const float* p_m2b     = (const float*)d_in[32];
  const float* a_b2m     = (const float*)d_in[33];
  const float* m_b2m     = (const float*)d_in[34];
  const float* p_b2m     = (const float*)d_in[35];
  const float* ln_g      = (const float*)d_in[36];
  const float* ln_b      = (const float*)d_in[37];

  char* ws = (char*)d_ws;
  size_t off = 0;
  auto take = [&](size_t bytes) -> char* {
    char* p = ws + off;
    off = (off + bytes + 255) & ~(size_t)255;
    return p;
  };
  float* h       = (float*)take((size_t)NN2 * HIDC * 4);
  float* agg     = (float*)take((size_t)NN2 * HIDC * 4);
  u16*   q       = (u16*)take((size_t)NN2 * HIDC * 2);
  u32*   kvt     = (u32*)take((size_t)NN2 * HIDC * 4);
  float* Wf      = (float*)take((size_t)2 * 64 * 192 * 4);
  float* bfv     = (float*)take((size_t)2 * 192 * 4);
  u32*   ghist   = (u32*)take((size_t)NBP * 4);
  u32*   bstart  = (u32*)take((size_t)(NB + 1) * 4);
  u32*   gcursor = (u32*)take((size_t)NBP * 4);
  u32*   bpairs  = (u32*)take((size_t)2 * NE * 4);

  const int tile_grid = 2 * KQV_BLKS;               // 3126
  const int fuse_grid = (2 * FUSE_T + 255) / 256;   // 98

  k_fuse<<<fuse_grid, 256, 0, stream>>>(
      q_w_mac, q_b_mac, k_w_mac, k_b_mac, v_w_mac, v_b_mac, a_m2b, m_m2b, p_m2b,
      q_w_buf, q_b_buf, k_w_buf, k_b_buf, v_w_buf, v_b_buf, a_b2m, m_b2m, p_b2m,
      Wf, bfv);
  hipMemsetAsync(ghist, 0, (size_t)NBP * 4, stream);
  k_bhist<<<SCGRID, 256, 0, stream>>>(ei_m2b, ei_b2m, ghist);
  k_enc2<<<tile_grid, 256, 0, stream>>>(
      x_mac, x_buf,
      enc_w_mac, enc_b_mac, enc_g_mac, enc_be_mac,
      enc_w_buf, enc_b_buf, enc_g_buf, enc_be_buf, h);
  k_bscan<<<1, 256, 0, stream>>>(ghist, bstart, gcursor);
  k_bscatter<<<SCGRID, 256, 0, stream>>>(ei_m2b, ei_b2m, gcursor, bpairs);
  k_kqv2<<<tile_grid, 256, 0, stream>>>(h, Wf, bfv, q, kvt);
  k_bedge2<<<2 * NB, 256, 0, stream>>>(bstart, bpairs, q, kvt, agg);
  k_out2<<<tile_grid, 256, 0, stream>>>(
      agg, h, o_w_mac, o_b_mac, skip_mac, o_w_buf, o_b_buf, skip_buf,
      ln_g, ln_b, (float*)d_out);
}